// Round 10
// baseline (620.568 us; speedup 1.0000x reference)
//
#include <hip/hip_runtime.h>
#include <math.h>

#define N_NODES 50000
#define M_PAD   50048    // N_NODES padded to multiple of 128 for MFMA tiles
#define N_EDGES 600000
#define E_TOT   650000   // N_EDGES + N_NODES (self loops appended)
#define F_IN    128
#define HID     64
#define HEADS   8
#define H1      512      // HEADS*HID
#define NCLS    16
#define NC      16
#define NCP     16
#define NBLK    ((N_NODES + 255) / 256)   // 196 scan blocks per array
#define FRNG    (N_NODES / 8)             // 6250 nodes per XCD range
#define FBPR    128                       // fill blocks per range
#define FPER    ((E_TOT + FBPR - 1) / FBPR)

typedef unsigned short u16;
typedef unsigned char  u8;
typedef __attribute__((ext_vector_type(8))) short short8;   // 8 bf16 = 4 VGPRs (MFMA A/B frag)
typedef __attribute__((ext_vector_type(4))) float f32x4;    // MFMA C/D frag
typedef __attribute__((ext_vector_type(2))) float f32x2;

__device__ __forceinline__ float bf2f(u16 h) {
    return __uint_as_float(((unsigned)h) << 16);
}
__device__ __forceinline__ u16 f2bf(float f) {
    unsigned u = __float_as_uint(f);
    u += 0x7fffu + ((u >> 16) & 1u);
    return (u16)(u >> 16);
}
__device__ __forceinline__ int edge_src(const int* __restrict__ ei, int e) {
    return (e < N_EDGES) ? ei[e] : (e - N_EDGES);
}
__device__ __forceinline__ int edge_dst(const int* __restrict__ ei, int e) {
    return (e < N_EDGES) ? ei[N_EDGES + e] : (e - N_EDGES);
}

// async global->LDS 16B copy: per-lane global src, wave-uniform LDS dest (+lane*16)
__device__ __forceinline__ void gload16(const void* g, void* l) {
    __builtin_amdgcn_global_load_lds(
        (const __attribute__((address_space(1))) unsigned int*)g,
        (__attribute__((address_space(3))) unsigned int*)l, 16, 0, 0);
}

// ---------------- CSR build ----------------
__global__ __launch_bounds__(256) void count_k(const int* __restrict__ ei,
                                               int* __restrict__ src_cnt, int* __restrict__ dst_cnt) {
    int e = blockIdx.x * 256 + threadIdx.x;
    if (e >= E_TOT) return;
    atomicAdd(&src_cnt[edge_src(ei, e)], 1);
    atomicAdd(&dst_cnt[edge_dst(ei, e)], 1);
}

// Phase A: per-block partial sums. grid = 2*NBLK (src blocks, then dst blocks).
__global__ __launch_bounds__(256) void scanA_k(const int* __restrict__ src_cnt,
                                               const int* __restrict__ dst_cnt,
                                               int* __restrict__ partials) {
    int pass = blockIdx.x >= NBLK;
    int b = blockIdx.x - pass * NBLK;
    const int* cnt = pass ? dst_cnt : src_cnt;
    int idx = b * 256 + threadIdx.x;
    int v = (idx < N_NODES) ? cnt[idx] : 0;
    __shared__ int red[4];
    #pragma unroll
    for (int off = 32; off; off >>= 1) v += __shfl_down(v, off, 64);
    if ((threadIdx.x & 63) == 0) red[threadIdx.x >> 6] = v;
    __syncthreads();
    if (threadIdx.x == 0) partials[blockIdx.x] = red[0] + red[1] + red[2] + red[3];
}

// Phase B: two independent exclusive scans of NBLK partials (src seg, dst seg), one block.
__global__ __launch_bounds__(512) void scanB_k(int* __restrict__ partials) {
    __shared__ int lds[512];
    int t = threadIdx.x;           // 512 threads: t<256 -> src segment, else dst
    int seg = t >> 8, i = t & 255;
    int v = (i < NBLK) ? partials[seg * NBLK + i] : 0;
    lds[t] = v;
    __syncthreads();
    for (int d = 1; d < 256; d <<= 1) {
        int x = (i >= d) ? lds[seg * 256 + i - d] : 0;
        __syncthreads();
        lds[t] += x;
        __syncthreads();
    }
    if (i < NBLK) partials[seg * NBLK + i] = lds[t] - v;   // exclusive
}

// Phase C: block-local exclusive scan + block offset -> off[]; off[N]=E_TOT constant.
__global__ __launch_bounds__(256) void scanC_k(const int* __restrict__ src_cnt,
                                               const int* __restrict__ dst_cnt,
                                               const int* __restrict__ partials,
                                               int* __restrict__ src_off, int* __restrict__ dst_off) {
    int pass = blockIdx.x >= NBLK;
    int b = blockIdx.x - pass * NBLK;
    const int* cnt = pass ? dst_cnt : src_cnt;
    int* off = pass ? dst_off : src_off;
    int base = partials[blockIdx.x];
    __shared__ int lds[256];
    int t = threadIdx.x;
    int idx = b * 256 + t;
    int v = (idx < N_NODES) ? cnt[idx] : 0;
    lds[t] = v;
    __syncthreads();
    for (int d = 1; d < 256; d <<= 1) {
        int x = (t >= d) ? lds[t - d] : 0;
        __syncthreads();
        lds[t] += x;
        __syncthreads();
    }
    if (idx < N_NODES) off[idx] = base + lds[t] - v;
    if (b == 0 && t == 0) off[N_NODES] = E_TOT;
}

// ---- fill pass D (XCD-range partitioned by dst): dsrc[slot]=src, deid[slot]=edge id.
__global__ __launch_bounds__(256) void fillD_k(const int* __restrict__ ei,
                                               const int* __restrict__ dst_off, int* __restrict__ dst_cur,
                                               int* __restrict__ deid, int* __restrict__ dsrc) {
    const int range = blockIdx.x & 7, slice = blockIdx.x >> 3;
    const int d0 = range * FRNG, d1 = d0 + FRNG;
    const int e0 = slice * FPER;
    const int e1 = (e0 + FPER < E_TOT) ? e0 + FPER : E_TOT;
    for (int e = e0 + threadIdx.x; e < e1; e += 256) {
        int d = edge_dst(ei, e);
        if (d < d0 || d >= d1) continue;
        int rd = dst_off[d] + atomicAdd(&dst_cur[d], 1);
        deid[rd] = e;
        dsrc[rd] = edge_src(ei, e);
    }
}

// ---- fill pass S (XCD-range partitioned by src): src_list[src slot] = dst-slot id.
__global__ __launch_bounds__(256) void fillS_k(const int* __restrict__ dsrc,
                                               const int* __restrict__ src_off, int* __restrict__ src_cur,
                                               int* __restrict__ src_list) {
    const int range = blockIdx.x & 7, slice = blockIdx.x >> 3;
    const int s0 = range * FRNG, s1 = s0 + FRNG;
    const int r0 = slice * FPER;
    const int r1 = (r0 + FPER < E_TOT) ? r0 + FPER : E_TOT;
    for (int rd = r0 + threadIdx.x; rd < r1; rd += 256) {
        int s = dsrc[rd];
        if (s < s0 || s >= s1) continue;
        src_list[src_off[s] + atomicAdd(&src_cur[s], 1)] = rd;
    }
}

// ---------------- layout converters ----------------
// f32 [M][K] row-major -> bf16 fragment-major Ap[K/8][Mp][8]; pad rows zeroed
__global__ __launch_bounds__(256) void conv_a_k(const float* __restrict__ A, u16* __restrict__ Ap,
                                                int M, int Mp, int K) {
    int i = blockIdx.x * 256 + threadIdx.x;
    int total = (K >> 3) * Mp;
    if (i >= total) return;
    int r = i % Mp;
    int kb = i / Mp;
    u16* o = Ap + (size_t)i * 8;
    u16 tmp[8];
    if (r < M) {
        const float* a = A + (size_t)r * K + kb * 8;
        #pragma unroll
        for (int j = 0; j < 8; ++j) tmp[j] = f2bf(a[j]);
    } else {
        #pragma unroll
        for (int j = 0; j < 8; ++j) tmp[j] = 0;
    }
    *(ushort4*)o = *(ushort4*)tmp;
    *(ushort4*)(o + 4) = *(ushort4*)(tmp + 4);
}

// f32 [K][N] row-major -> bf16 fragment-major Bp[K/8][N][8] (Bp[kb][n][j] = B[kb*8+j][n])
__global__ __launch_bounds__(256) void conv_b_k(const float* __restrict__ B, u16* __restrict__ Bp,
                                                int K, int N) {
    int i = blockIdx.x * 256 + threadIdx.x;
    int total = (K >> 3) * N;
    if (i >= total) return;
    int n = i % N;
    int kb = i / N;
    u16 tmp[8];
    #pragma unroll
    for (int j = 0; j < 8; ++j) tmp[j] = f2bf(B[(size_t)(kb * 8 + j) * N + n]);
    u16* o = Bp + (size_t)i * 8;
    *(ushort4*)o = *(ushort4*)tmp;
    *(ushort4*)(o + 4) = *(ushort4*)(tmp + 4);
}

// per-lane B-frag layout tables for MFMA 16x16x32
__device__ __forceinline__ void wfrag_one(const float* W, u16* o, int i, int K, int N) {
    int j = i & 7, lane = (i >> 3) & 63, rest = i >> 9;
    int nt = rest % (N / 16), ks = rest / (N / 16);
    int lm = lane & 15, quad = lane >> 4;
    int k = ks * 32 + quad * 8 + j, n = nt * 16 + lm;
    o[i] = (k < K) ? f2bf(W[(size_t)k * N + n]) : (u16)0;
}
// residual table: lo = bf16(W - bf16(W)) so hi+lo MFMA pair == f32-precision W
__device__ __forceinline__ void wfrag_res(const float* W, u16* o, int i, int K, int N) {
    int j = i & 7, lane = (i >> 3) & 63, rest = i >> 9;
    int nt = rest % (N / 16), ks = rest / (N / 16);
    int lm = lane & 15, quad = lane >> 4;
    int k = ks * 32 + quad * 8 + j, n = nt * 16 + lm;
    float w = (k < K) ? W[(size_t)k * N + n] : 0.f;
    o[i] = f2bf(w - bf2f(f2bf(w)));
}
__global__ __launch_bounds__(256) void wfrag_all_k(
    const float* __restrict__ h1w1, const float* __restrict__ h1w2,
    const float* __restrict__ h2w1, const float* __restrict__ h2w2,
    const float* __restrict__ W2,
    u16* __restrict__ w1f, u16* __restrict__ w2f,
    u16* __restrict__ w3f, u16* __restrict__ w4f,
    u16* __restrict__ w2hf, u16* __restrict__ w2lf) {
    int i = blockIdx.x * 256 + threadIdx.x;   // total 7168 + 2*8192 = 23552
    if (i < 2048)       wfrag_one(h1w1, w1f, i, 16, 64);          // Kpad 32, N 64
    else if (i < 6144)  wfrag_one(h1w2, w2f, i - 2048, 64, 64);   // Kpad 64, N 64
    else if (i < 6656)  wfrag_one(h2w1, w3f, i - 6144, 16, 16);
    else if (i < 7168)  wfrag_one(h2w2, w4f, i - 6656, 16, 16);
    else if (i < 15360) wfrag_one(W2, w2hf, i - 7168, 512, 16);   // W2 hi frags (16 ks chunks)
    else if (i < 23552) wfrag_res(W2, w2lf, i - 15360, 512, 16);  // W2 lo (residual) frags
}

// ---------------- MFMA GEMM: frag-major operands, 128x128 tile, 4 waves ----------------
// K-loop (round-9 proven): A triple-buffered in LDS (3x8KB) with counted-vmcnt depth-2
// prefetch; B (L2-hot) in REGISTERS with depth-1 ping-pong; B(ts) issued before A(ts+1)
// so B-waits never retire the A prefetch. LDS 32KB (epilogue Tf aliases the A buffers;
// Hs aliases Tf's first half) and __launch_bounds__(256,4) -> 4 blocks/CU.
// EPI==1 (x @ W1 path): h1 = acc is NOT stored as bf16; the epilogue applies the
//   ex-s1inv phase-2 chain directly: y = bf2f(f2bf(acc)) * sinv[row][ch&63] -> fp8
//   (identical rounding/pack order to the old xb round-trip) and writes the 512B-stride
//   fp8 gather table (half the bytes, no re-read). Requires sinv precomputed (s1sum_k).
// EPI==3 (t1 @ p1w2 path): h = relu(extra + bias2 + alpha*leaky(acc + bias, 0.01)) is
//   NOT stored; bf16(h) goes through the XOR-swizzled Hs tile and the MATRIX pipe:
//   xh2 partial = h @ (W2hi+W2lo), W2 frags loaded per-kc from L2-hot tables.
template<int EPI>
__global__ __launch_bounds__(256, 4) void mfma_gemm_k(
    const u16* __restrict__ Ap, const u16* __restrict__ Bp, u16* __restrict__ C,
    int M, int Mp, int Nn, int K,
    const float* __restrict__ bias, const u16* __restrict__ extra,
    const float* __restrict__ bias2, const float* __restrict__ alpha_p,
    const u16* __restrict__ w2hf, const u16* __restrict__ w2lf,
    float* __restrict__ xh2p, const float* __restrict__ sinvp)
{
    __shared__ __align__(16) char LSD[32768];   // loop: 3x8KB A bufs; epilogue: Tf 32KB
    const int t = threadIdx.x;
    const int wave = t >> 6, lane = t & 63;
    const int wm = (wave >> 1) * 64, wn = (wave & 1) * 64;
    const int lm = lane & 15, quad = lane >> 4;

    // bijective XCD-chunk swizzle (m204 formula); dispatch->XCD assumed bid%8.
    const int nwg = (int)(gridDim.y << 2);
    const int bid = (int)(blockIdx.y * 4 + blockIdx.x);
    const int qq = nwg >> 3, rr8 = nwg & 7;
    const int xcd = bid & 7, idx = bid >> 3;
    const int wg = (xcd < rr8 ? xcd * (qq + 1) : rr8 * (qq + 1) + (xcd - rr8) * qq) + idx;
    const int bn = (wg & 3) * 128;
    const int bm = (wg >> 2) * 128;

    const char* Ab = (const char*)Ap;
    size_t cbase[4];
    #pragma unroll
    for (int nj = 0; nj < 4; ++nj) cbase[nj] = (size_t)(bn + wn + nj * 16 + lm) * 8;

    f32x4 acc[4][4] = {};
    const int NT = K >> 5;   // K-steps of 32 (4 or 16, even)

    // stage K-step ts's A tile (8 KB) into buffer b: 2 gload16 per wave
    auto stageA = [&](int b, int ts) {
        const int kb0 = ts * 4;
        #pragma unroll
        for (int h = 0; h < 2; ++h) {
            const int ob = h * 4096 + wave * 1024;     // wave-uniform LDS byte base
            const int kb = kb0 + (ob >> 11);           // which k/8 chunk
            const int rem = (ob & 1024) + lane * 16;   // byte offset inside 2 KB chunk
            gload16(Ab + ((size_t)kb * Mp + bm) * 16 + rem, LSD + b * 8192 + ob);
        }
    };
    // B fragments for K-step ts: 4 x 16B per lane, straight from L2
    auto loadB = [&](short8 (&bf)[4], int ts) {
        const u16* Bq = Bp + (size_t)(ts * 4 + quad) * Nn * 8;
        #pragma unroll
        for (int nj = 0; nj < 4; ++nj) bf[nj] = *(const short8*)(Bq + cbase[nj]);
    };
    auto compute = [&](int cb, short8 (&bf)[4]) {
        const u16* As = (const u16*)(LSD + cb * 8192);
        short8 af[4];
        #pragma unroll
        for (int mi = 0; mi < 4; ++mi)
            af[mi] = *(const short8*)(As + quad * 1024 + (wm + mi * 16 + lm) * 8);
        #pragma unroll
        for (int mi = 0; mi < 4; ++mi)
            #pragma unroll
            for (int nj = 0; nj < 4; ++nj)
                acc[mi][nj] = __builtin_amdgcn_mfma_f32_16x16x32_bf16(af[mi], bf[nj], acc[mi][nj], 0, 0, 0);
    };

    short8 b0[4], b1[4];
    stageA(0, 0);        // A0 (oldest)
    loadB(b0, 0);        // B0 before A1: B-waits never retire the A prefetch
    stageA(1, 1);        // A1
    #pragma unroll 1
    for (int ts = 0; ts < NT - 2; ts += 2) {
        asm volatile("s_waitcnt vmcnt(6)" ::: "memory");   // A(ts) landed (mine)
        __builtin_amdgcn_sched_barrier(0);
        __builtin_amdgcn_s_barrier();                      // => everyone's A(ts) landed
        loadB(b1, ts + 1);
        stageA((ts + 2) % 3, ts + 2);
        compute(ts % 3, b0);
        asm volatile("s_waitcnt vmcnt(6)" ::: "memory");   // A(ts+1) landed
        __builtin_amdgcn_sched_barrier(0);
        __builtin_amdgcn_s_barrier();
        loadB(b0, ts + 2);
        stageA((ts + 3) % 3, ts + 3);
        compute((ts + 1) % 3, b1);
    }
    // ts = NT-2
    asm volatile("s_waitcnt vmcnt(6)" ::: "memory");
    __builtin_amdgcn_sched_barrier(0);
    __builtin_amdgcn_s_barrier();
    loadB(b1, NT - 1);
    compute((NT - 2) % 3, b0);
    // ts = NT-1
    asm volatile("s_waitcnt vmcnt(4)" ::: "memory");       // A(NT-1) landed
    __builtin_amdgcn_sched_barrier(0);
    __builtin_amdgcn_s_barrier();
    compute((NT - 1) % 3, b1);
    __syncthreads();            // full rendezvous before epilogue reuses LSD

    // ---- epilogue: acc -> 64x128 f32 LDS tile Tf (XOR swizzle) -> consume ----
    float* Tf = (float*)LSD;
    const float alpha = (EPI == 3) ? *alpha_p : 0.f;
    #pragma unroll
    for (int pass = 0; pass < 2; ++pass) {
        if ((wave >> 1) == pass) {
            #pragma unroll
            for (int mi = 0; mi < 4; ++mi)
                #pragma unroll
                for (int r4 = 0; r4 < 4; ++r4) {
                    const int lr = mi * 16 + quad * 4 + r4;
                    const int sw = (lr & 7) << 2;
                    #pragma unroll
                    for (int nj = 0; nj < 4; ++nj)
                        Tf[lr * 128 + ((wn + nj * 16 + lm) ^ sw)] = acc[mi][nj][r4];
                }
        }
        __syncthreads();
        if (EPI == 1) {
            // fused ex-s1inv phase 2: y = bf16round(acc) * sinv -> fp8 table (512B rows)
            const int lrow = t & 63, chunk = t >> 6;
            const int col0 = chunk * 32;
            const int rr = bm + pass * 64 + lrow;
            if (rr < M) {
                const int sw = (lrow & 7) << 2;
                float v[32];
                #pragma unroll
                for (int j4 = 0; j4 < 8; ++j4) {
                    float4 f = *(const float4*)&Tf[lrow * 128 + ((col0 + j4 * 4) ^ sw)];
                    v[j4 * 4] = f.x; v[j4 * 4 + 1] = f.y; v[j4 * 4 + 2] = f.z; v[j4 * 4 + 3] = f.w;
                }
                const int gc0 = bn + col0;
                const float* sv = sinvp + (size_t)rr * 64 + (gc0 & 63);  // 32 consecutive
                int pw[8];
                #pragma unroll
                for (int g = 0; g < 8; ++g) {
                    float y0 = bf2f(f2bf(v[g * 4 + 0])) * sv[g * 4 + 0];
                    float y1 = bf2f(f2bf(v[g * 4 + 1])) * sv[g * 4 + 1];
                    float y2 = bf2f(f2bf(v[g * 4 + 2])) * sv[g * 4 + 2];
                    float y3 = bf2f(f2bf(v[g * 4 + 3])) * sv[g * 4 + 3];
                    int p0 = __builtin_amdgcn_cvt_pk_fp8_f32(y0, y1, 0, false);
                    pw[g] = __builtin_amdgcn_cvt_pk_fp8_f32(y2, y3, p0, true);
                }
                u8* dst = (u8*)C + (size_t)rr * 512 + gc0;
                *(uint4*)dst        = make_uint4(pw[0], pw[1], pw[2], pw[3]);
                *(uint4*)(dst + 16) = make_uint4(pw[4], pw[5], pw[6], pw[7]);
            }
        } else {
            u8* HsB = (u8*)LSD;                  // aliases Tf's first 16KB (barrier-guarded)
            const int row = wave * 16 + lm;      // 0..63 (one h-row per lane)
            const int col0 = quad * 32;
            const int rr = bm + pass * 64 + row;
            const int gc0 = bn + col0;
            u16 hpk[32];
            if (rr < M) {
                const int sw = (row & 7) << 2;
                const u16* ex = extra + (size_t)rr * Nn + gc0;
                #pragma unroll
                for (int g = 0; g < 4; ++g) {
                    float4 f0 = *(const float4*)&Tf[row * 128 + ((col0 + g * 8) ^ sw)];
                    float4 f1 = *(const float4*)&Tf[row * 128 + ((col0 + g * 8 + 4) ^ sw)];
                    float vv8[8] = {f0.x, f0.y, f0.z, f0.w, f1.x, f1.y, f1.z, f1.w};
                    short8 e8 = *(const short8*)(ex + g * 8);
                    #pragma unroll
                    for (int j = 0; j < 8; ++j) {
                        const int cj = g * 8 + j;
                        float vv = vv8[j] + bias[gc0 + cj];
                        vv = vv > 0.f ? vv : 0.01f * vv;
                        float o = bf2f((u16)e8[j]) + bias2[gc0 + cj] + alpha * vv;
                        o = fmaxf(o, 0.f);
                        hpk[cj] = f2bf(o);      // identical to the old hb bf16 value
                    }
                }
            } else {
                #pragma unroll
                for (int j = 0; j < 32; ++j) hpk[j] = 0;
            }
            __syncthreads();                     // all Tf reads done before Hs overwrite
            // bf16 h row -> Hs (XOR-swizzled 16B slots: bank-clean write AND read)
            #pragma unroll
            for (int g = 0; g < 4; ++g) {
                const int ba = (row * 256 + quad * 64 + g * 16) ^ ((row & 7) << 4);
                *(short8*)(HsB + ba) = *(const short8*)&hpk[g * 8];
            }
            __syncthreads();
            // A-frags from Hs; xh2 partial = h @ (W2hi + W2lo) on the matrix pipe.
            // W2 hi/lo frags loaded per-kc from L2-hot tables (transient regs).
            f32x4 axh = {};
            const int ksb = bn >> 5;
            #pragma unroll
            for (int kc = 0; kc < 4; ++kc) {
                const int ba = (row * 256 + kc * 64 + quad * 16) ^ ((row & 7) << 4);
                short8 ha = *(const short8*)(HsB + ba);
                short8 wh = *(const short8*)(w2hf + ((size_t)(ksb + kc) * 64 + lane) * 8);
                short8 wl = *(const short8*)(w2lf + ((size_t)(ksb + kc) * 64 + lane) * 8);
                axh = __builtin_amdgcn_mfma_f32_16x16x32_bf16(ha, wh, axh, 0, 0, 0);
                axh = __builtin_amdgcn_mfma_f32_16x16x32_bf16(ha, wl, axh, 0, 0, 0);
            }
            // C/D layout: col = lane&15, row = quad*4 + reg
            #pragma unroll
            for (int r = 0; r < 4; ++r) {
                const int prow = bm + pass * 64 + wave * 16 + quad * 4 + r;
                if (prow < M)
                    xh2p[((size_t)(bn >> 7) * M_PAD + prow) * 16 + lm] = axh[r];
            }
        }
        __syncthreads();
    }
}

// ---------------- xh2 = sum of 4 bn-partials ----------------
__global__ __launch_bounds__(256) void red4_k(const float* __restrict__ xh2p,
                                              float* __restrict__ xh2) {
    int i = blockIdx.x * 256 + threadIdx.x;     // float4 index over [N_NODES][16]
    if (i >= N_NODES * 4) return;
    const float4* P = (const float4*)xh2p;
    const size_t S = (size_t)M_PAD * 4;         // float4s per slice
    float4 a = P[i], b = P[S + i], c = P[2 * S + i], d = P[3 * S + i];
    float4 r;
    r.x = (a.x + b.x) + (c.x + d.x);
    r.y = (a.y + b.y) + (c.y + d.y);
    r.z = (a.z + b.z) + (c.z + d.z);
    r.w = (a.w + b.w) + (c.w + d.w);
    ((float4*)xh2)[i] = r;
}

// ---------------- t1 = leaky(ep @ p1w1, 0.2), K=16, written in frag-major Ap layout ----------------
__global__ __launch_bounds__(256) void gemm_t1_k(
    const float* __restrict__ ep, const float* __restrict__ W, u16* __restrict__ t1p)
{
    __shared__ float Bs[16][64];
    const int bm = blockIdx.y * 64, bn = blockIdx.x * 64;
    const int t = threadIdx.x;
    const int tx = t & 15, ty = t >> 4;
    *(float4*)&Bs[t >> 4][(t & 15) * 4] = *(const float4*)&W[(size_t)(t >> 4) * H1 + bn + (t & 15) * 4];
    __syncthreads();
    const int r0 = bm + ty * 4;
    const int c0 = bn + tx * 4;
    for (int i = 0; i < 4; ++i) {
        int r = r0 + i;
        if (r >= N_NODES) continue;
        float av[16];
        #pragma unroll
        for (int j4 = 0; j4 < 16; j4 += 4) {
            float4 v = *(const float4*)(ep + (size_t)r * NCP + j4);
            av[j4] = v.x; av[j4 + 1] = v.y; av[j4 + 2] = v.z; av[j4 + 3] = v.w;
        }
        u16 pk[4];
        #pragma unroll
        for (int q = 0; q < 4; ++q) {
            float s = 0.f;
            #pragma unroll
            for (int k = 0; k < 16; ++k) s = fmaf(av[k], Bs[k][tx * 4 + q], s);
            s = s > 0.f ? s : 0.2f * s;
            pk[q] = f2bf(s);
        }
        u16* o = t1p + ((size_t)(c0 >> 3) * M_PAD + r) * 8 + (c0 & 7);
        *(ushort4*)o = *(ushort4*)pk;
    }
}

// ---------------- fused MFMA edge MLPs, SLOT-ordered: gather kr via deid, ----------------
// ---------------- write ebd / ebd2 fully sequentially (no scatter)        ----------------
#define TSTR 72   // LDS tile row stride in bf16 elems (144 B: 16B-aligned frag reads, <=2-way banks)
__global__ __launch_bounds__(256) void edge_mlps_k(
    const float* __restrict__ kr, const int* __restrict__ deid,
    const u16* __restrict__ w1f, const u16* __restrict__ w2f, const float* __restrict__ b2a,
    const u16* __restrict__ w3f, const u16* __restrict__ w4f, const float* __restrict__ b2b,
    u16* __restrict__ ebd, u16* __restrict__ ebd2)
{
    __shared__ __align__(16) u16 T[4][16 * TSTR];
    const int t = threadIdx.x, wv = t >> 6, lane = t & 63;
    const int lm = lane & 15, quad = lane >> 4;
    const int tile = blockIdx.x * 4 + wv;
    const int s0 = tile * 16;          // dst-slot base (16 consecutive slots)
    if (s0 >= E_TOT) return;
    u16* Tw = T[wv];

    // weight fragments -> VGPRs (per-lane)
    short8 W1[4], W2[2][4];
    #pragma unroll
    for (int nt = 0; nt < 4; ++nt) W1[nt] = *(const short8*)(w1f + ((size_t)nt * 64 + lane) * 8);
    #pragma unroll
    for (int ks = 0; ks < 2; ++ks)
        #pragma unroll
        for (int nt = 0; nt < 4; ++nt)
            W2[ks][nt] = *(const short8*)(w2f + (((size_t)ks * 4 + nt) * 64 + lane) * 8);
    short8 W3 = *(const short8*)(w3f + (size_t)lane * 8);
    short8 W4 = *(const short8*)(w4f + (size_t)lane * 8);
    float b2av[4];
    #pragma unroll
    for (int nt = 0; nt < 4; ++nt) b2av[nt] = b2a[nt * 16 + lm];
    float b2bv = b2b[lm];

    // A-frag: slot row m = s0+lm -> edge e = deid[s0+lm]; k = quad*8+j (K=16 padded to 32)
    const int e = deid[s0 + lm];
    short8 af = {};
    if (quad < 2) {
        const float* kp = kr + (size_t)e * NC + quad * 8;
        float4 v0 = *(const float4*)kp;
        float4 v1 = *(const float4*)(kp + 4);
        u16 tmp[8] = {f2bf(v0.x), f2bf(v0.y), f2bf(v0.z), f2bf(v0.w),
                      f2bf(v1.x), f2bf(v1.y), f2bf(v1.z), f2bf(v1.w)};
        af = *(const short8*)tmp;
    }

    // ---- MLP1 layer 1: [16 slots x 64] = kr @ w1, leaky 0.2 ----
    f32x4 a1[4] = {};
    #pragma unroll
    for (int nt = 0; nt < 4; ++nt)
        a1[nt] = __builtin_amdgcn_mfma_f32_16x16x32_bf16(af, W1[nt], a1[nt], 0, 0, 0);
    #pragma unroll
    for (int nt = 0; nt < 4; ++nt)
        #pragma unroll
        for (int r = 0; r < 4; ++r) {
            float v = a1[nt][r];
            v = v > 0.f ? v : 0.2f * v;
            Tw[(quad * 4 + r) * TSTR + nt * 16 + lm] = f2bf(v);
        }
    __builtin_amdgcn_s_waitcnt(0);   // drain LDS writes before same-wave reads

    // ---- MLP1 layer 2: K=64 from LDS tile ----
    short8 a2[2];
    #pragma unroll
    for (int ks = 0; ks < 2; ++ks)
        a2[ks] = *(const short8*)&Tw[lm * TSTR + ks * 32 + quad * 8];
    f32x4 c2[4] = {};
    #pragma unroll
    for (int nt = 0; nt < 4; ++nt)
        #pragma unroll
        for (int ks = 0; ks < 2; ++ks)
            c2[nt] = __builtin_amdgcn_mfma_f32_16x16x32_bf16(a2[ks], W2[ks][nt], c2[nt], 0, 0, 0);
    // epilogue: + b2, exp -> LDS
    #pragma unroll
    for (int nt = 0; nt < 4; ++nt)
        #pragma unroll
        for (int r = 0; r < 4; ++r)
            Tw[(quad * 4 + r) * TSTR + nt * 16 + lm] = f2bf(__expf(c2[nt][r] + b2av[nt]));
    __builtin_amdgcn_s_waitcnt(0);
    // repack: rows are consecutive slots -> 2 KB fully-contiguous store per wave
    #pragma unroll
    for (int p = 0; p < 2; ++p) {
        int c = p * 64 + lane;
        int row = c >> 3, off = (c & 7) * 8;
        short8 v = *(const short8*)&Tw[row * TSTR + off];
        *(short8*)(ebd + (size_t)(s0 + row) * HID + off) = v;
    }

    // ---- MLP2 (16->16->16), reuses kr A-frag ----
    f32x4 b1 = __builtin_amdgcn_mfma_f32_16x16x32_bf16(af, W3, (f32x4){}, 0, 0, 0);
    __builtin_amdgcn_s_waitcnt(0);   // eb repack reads done before overwrite
    #pragma unroll
    for (int r = 0; r < 4; ++r) {
        float v = b1[r];
        v = v > 0.f ? v : 0.2f * v;
        Tw[(quad * 4 + r) * TSTR + lm] = f2bf(v);
    }
    __builtin_amdgcn_s_waitcnt(0);
    // A-frag: cols 16..31 hold stale finite values, but W4 is zero there -> no effect
    short8 a3 = *(const short8*)&Tw[lm * TSTR + quad * 8];
    f32x4 c3 = __builtin_amdgcn_mfma_f32_16x16x32_bf16(a3, W4, (f32x4){}, 0, 0, 0);
    #pragma unroll
    for (int r = 0; r < 4; ++r)
        Tw[(quad * 4 + r) * TSTR + lm] = f2bf(__expf(c3[r] + b2bv));
    __builtin_amdgcn_s_waitcnt(0);
    if (lane < 32) {
        int row = lane >> 1, off = (lane & 1) * 8;
        short8 v = *(const short8*)&Tw[row * TSTR + off];
        *(short8*)(ebd2 + (size_t)(s0 + row) * NCLS + off) = v;   // 512 B contiguous per wave
    }
}

// ---------------- layer-1 softmax denominator only (wave per src) -> sinv[N][64] ----------------
__global__ __launch_bounds__(256) void s1sum_k(
    const u16* __restrict__ ebd, const int* __restrict__ src_off, const int* __restrict__ src_list,
    float* __restrict__ sinv)
{
    int gid = blockIdx.x * 256 + threadIdx.x;
    int wid = gid >> 6, lane = gid & 63;
    if (wid >= N_NODES) return;
    int o0 = src_off[wid], o1 = src_off[wid + 1];
    float s0 = 0.f, s1 = 0.f, s2 = 0.f, s3 = 0.f;
    int i = o0;
    for (; i + 3 < o1; i += 4) {
        int l0 = src_list[i], l1 = src_list[i + 1], l2 = src_list[i + 2], l3 = src_list[i + 3];
        s0 += bf2f(ebd[(size_t)l0 * HID + lane]);
        s1 += bf2f(ebd[(size_t)l1 * HID + lane]);
        s2 += bf2f(ebd[(size_t)l2 * HID + lane]);
        s3 += bf2f(ebd[(size_t)l3 * HID + lane]);
    }
    for (; i < o1; ++i) {
        int sl = src_list[i];
        s0 += bf2f(ebd[(size_t)sl * HID + lane]);
    }
    sinv[(size_t)wid * 64 + lane] = 1.f / (((s0 + s1) + (s2 + s3)) + 1e-16f);
}

// ---------------- message pass 1: wave per dst, sequential slots, fp8 gather, unroll 4 ----------------
__global__ __launch_bounds__(256) void msg1_k(
    const u16* __restrict__ ebd, const u8* __restrict__ xq,
    const int* __restrict__ dsrc, const int* __restrict__ dst_off,
    u16* __restrict__ aggb)
{
    int gid = blockIdx.x * 256 + threadIdx.x;
    int wid = gid >> 6, lane = gid & 63;
    if (wid >= N_NODES) return;
    int o0 = dst_off[wid], o1 = dst_off[wid + 1];
    const int a_off = (lane & 7) * 8;     // alpha channel block (ch = lane*8+j mod 64)
    float acc[8] = {};
    int i = o0;
    for (; i + 3 < o1; i += 4) {
        int s0 = __builtin_nontemporal_load(dsrc + i);
        int s1 = __builtin_nontemporal_load(dsrc + i + 1);
        int s2 = __builtin_nontemporal_load(dsrc + i + 2);
        int s3 = __builtin_nontemporal_load(dsrc + i + 3);
        short8 a0 = __builtin_nontemporal_load((const short8*)(ebd + (size_t)i * HID + a_off));
        short8 a1 = __builtin_nontemporal_load((const short8*)(ebd + (size_t)(i + 1) * HID + a_off));
        short8 a2 = __builtin_nontemporal_load((const short8*)(ebd + (size_t)(i + 2) * HID + a_off));
        short8 a3 = __builtin_nontemporal_load((const short8*)(ebd + (size_t)(i + 3) * HID + a_off));
        uint2 q0 = *(const uint2*)(xq + (size_t)s0 * 512 + lane * 8);
        uint2 q1 = *(const uint2*)(xq + (size_t)s1 * 512 + lane * 8);
        uint2 q2 = *(const uint2*)(xq + (size_t)s2 * 512 + lane * 8);
        uint2 q3 = *(const uint2*)(xq + (size_t)s3 * 512 + lane * 8);
        const uint2 qs[4] = {q0, q1, q2, q3};
        const short8 as[4] = {a0, a1, a2, a3};
        #pragma unroll
        for (int u = 0; u < 4; ++u) {
            f32x2 d0 = __builtin_amdgcn_cvt_pk_f32_fp8((int)qs[u].x, false);
            f32x2 d1 = __builtin_amdgcn_cvt_pk_f32_fp8((int)qs[u].x, true);
            f32x2 d2 = __builtin_amdgcn_cvt_pk_f32_fp8((int)qs[u].y, false);
            f32x2 d3 = __builtin_amdgcn_cvt_pk_f32_fp8((int)qs[u].y, true);
            float xv[8] = {d0.x, d0.y, d1.x, d1.y, d2.x, d2.y, d3.x, d3.y};
            #pragma unroll
            for (int j = 0; j < 8; ++j)
                acc[j] = fmaf(bf2f((u16)as[u][j]), xv[j], acc[j]);
        }
    }
    for (; i < o1; ++i) {
        int s = __builtin_nontemporal_load(dsrc + i);
        short8 a8 = __builtin_nontemporal_load((const short8*)(ebd + (size_t)i * HID + a_off));
        uint2 q = *(const uint2*)(xq + (size_t)s * 512 + lane * 8);
        f32x2 d0 = __builtin_amdgcn_cvt_pk_f32_fp8((int)q.x, false);
        f32x2 d1 = __builtin_amdgcn_cvt_pk_f32_fp8((int)q.x, true);
        f32x2 d2 = __builtin_amdgcn_cvt_pk_f32_fp8((int)q.y, false);
        f32x2 d3 = __builtin_amdgcn_cvt_pk_f32_fp8((int)q.y, true);
        float xv[8] = {d0.x, d0.y, d1.x, d1.y, d2.x, d2.y, d3.x, d3.y};
        #pragma unroll
        for (int j = 0; j < 8; ++j)
            acc[j] = fmaf(bf2f((u16)a8[j]), xv[j], acc[j]);
    }
    u16 pk[8];
    #pragma unroll
    for (int j = 0; j < 8; ++j) pk[j] = f2bf(acc[j]);
    __builtin_nontemporal_store(*(const short8*)pk, (short8*)(aggb + (size_t)wid * H1 + lane * 8));
}

// ---------------- inverse denominator, layer 2 (16 threads per src) ----------------
__global__ __launch_bounds__(256) void s2sum_k(
    const u16* __restrict__ ebd2, const int* __restrict__ src_off, const int* __restrict__ src_list,
    float* __restrict__ inv2)
{
    int t = threadIdx.x;
    int g = blockIdx.x * 16 + (t >> 4), c = t & 15;
    if (g >= N_NODES) return;
    int o0 = src_off[g], o1 = src_off[g + 1];
    float sum = 0.f;
    for (int i = o0; i < o1; ++i) {
        int sl = src_list[i];
        sum += bf2f(ebd2[(size_t)sl * NCLS + c]);
    }
    inv2[(size_t)g * NCLS + c] = 1.f / (sum + 1e-16f);
}

// ---------------- message pass 2 (16 threads per dst), sequential slots ----------------
__global__ __launch_bounds__(256) void msg2_k(
    const u16* __restrict__ ebd2, const float* __restrict__ inv2,
    const float* __restrict__ xh2, const int* __restrict__ dsrc,
    const int* __restrict__ dst_off, float* __restrict__ agg2)
{
    int t = threadIdx.x;
    int g = blockIdx.x * 16 + (t >> 4), c = t & 15;
    if (g >= N_NODES) return;
    int o0 = dst_off[g], o1 = dst_off[g + 1];
    float acc = 0.f;
    for (int i = o0; i < o1; ++i) {
        int s = dsrc[i];
        float a = bf2f(ebd2[(size_t)i * NCLS + c]) * inv2[(size_t)s * NCLS + c];
        acc = fmaf(a, xh2[(size_t)s * NCLS + c], acc);
    }
    agg2[(size_t)g * NCLS + c] = acc;
}

// ---------------- final: o = agg2 + bias2 + alpha*p2; log_softmax ----------------
__global__ __launch_bounds__(256) void final_k(
    const float* __restrict__ agg2, const float* __restrict__ ep,
    const float* __restrict__ pw1, const float* __restrict__ pw2,
    const float* __restrict__ pb2, const float* __restrict__ bias,
    const float* __restrict__ alpha_p, float* __restrict__ out)
{
    __shared__ float s1w[256], s2w[256], sb[16], sbias[16];
    const int t = threadIdx.x;
    s1w[t] = pw1[t];
    s2w[t] = pw2[t];
    if (t < 16) { sb[t] = pb2[t]; sbias[t] = bias[t]; }
    __syncthreads();
    const int v = blockIdx.x * 256 + t;
    if (v >= N_NODES) return;
    float alpha = *alpha_p;
    float e_[16];
    #pragma unroll
    for (int j4 = 0; j4 < 16; j4 += 4) {
        float4 vv = *(const float4*)(ep + (size_t)v * 16 + j4);
        e_[j4] = vv.x; e_[j4 + 1] = vv.y; e_[j4 + 2] = vv.z; e_[j4 + 3] = vv.w;
    }
    float t2[16];
    #pragma unroll
    for (int c = 0; c < 16; ++c) {
        float s = 0.f;
        #pragma unroll
        for (int j = 0; j < 16; ++j) s = fmaf(e_[j], s1w[j * 16 + c], s);
        t2[c] = s > 0.f ? s : 0.2f * s;
    }
    float o[16];
    #pragma unroll
    for (int c4 = 0; c4 < 16; c4 += 4) {
        float4 ag = *(const float4*)(agg2 + (size_t)v * 16 + c4);
        float agv[4] = {ag.x, ag.y, ag.z, ag.w};
        #pragma unroll
        for (int q = 0; q < 4; ++q) {
            int c = c4 + q;
            float p = sb[c];
            #pragma unroll
            for (int j = 0; j < 16; ++j) p = fmaf(t2[j], s2w[j * 16 + c], p);
            p = p > 0.f ? p : 0.01f * p;
            o[c] = agv[q] + sbias[c] + alpha * p;
        }
    }
    float mx = o[0];
    #pragma unroll
    for (int c = 1; c < 16; ++c) mx = fmaxf(mx, o[c]);
    float se = 0.f;
    #pragma unroll
    for (int c = 0; c < 16; ++c) se += expf(o[c] - mx);
    float lse = mx + logf(se);
    #pragma unroll
    for (int c4 = 0; c4 < 16; c4 += 4)
        *(float4*)(out + (size_t)v * 16 + c4) =
            make_float4(o[c4] - lse, o[c4 + 1] - lse, o[c4 + 2] - lse, o[c4 + 3] - lse);
}

extern "C" void kernel_launch(void* const* d_in, const int* in_sizes, int n_in,
                              void* d_out, int out_size, void* d_ws, size_t ws_size,
                              hipStream_t stream) {
    const float* x    = (const float*)d_in[0];
    const int*   ei   = (const int*)d_in[1];
    const float* alpha= (const float*)d_in[2];
    const float* kr   = (const float*)d_in[3];
    const float* ep   = (const float*)d_in[4];
    const float* W1   = (const float*)d_in[5];
    const float* h1w1 = (const float*)d_in[6];
    const float* h1w2 = (const float*)d_in[7];
    const float* h1b2 = (const float*)d_in[8];
    const float* p1w1 = (const float*)d_in[9];
    const float* p1w2 = (const float*)d_in[10];
    const float* p1b2 = (const float*)d_in[11];
    const float* b1   = (const float*)d_in[12];
    const float* W2   = (const float*)d_in[13];
    const float* h2w1 = (const float*)d_in[14];
    const float* h2w2 = (const float*)d_in[15];
    const float* h2b2 = (const float*)d_in[16];
    const float* p2w1 = (const float*)d_in[17];
    const float* p2w2 = (const float*)d_in[18];
    const float* p2b2 = (const float*)d_in[19];
    const float* b2   = (const float*)d_in[20];
    float* out = (float*)d_out;

    // ---- workspace bump allocator (~242 MB) ----
    char* p = (char*)d_ws;
    auto alloc = [&](size_t bytes) { char* r = p; p += (bytes + 255) & ~(size_t)255; return r; };

    char* r0    = alloc((size_t)64 * M_PAD * 16);          // 51.25 MB: xq (fp8 512B rows), then t1p
    u8*   xq    = (u8*)r0;
    u16*  t1p   = (u16*)r0;
    u16*  aggb  = (u16*)alloc((size_t)N_NODES * H1 * 2);   // 51.2 MB bf16
    char* ebr   = alloc((size_t)E_TOT * HID * 2);          // 83.2 MB: ebd (slot-ordered)
    u16*  ebd   = (u16*)ebr;
    u16*  ebd2  = (u16*)alloc((size_t)E_TOT * NCLS * 2);   // 20.8 MB
    char* xpr   = alloc((size_t)16 * M_PAD * 16);          // 12.81 MB: xp (frag-major x), then xh2p[4][M_PAD][16]
    u16*  xp    = (u16*)xpr;
    float* xh2p = (float*)xpr;
    float* sinv1= (float*)alloc((size_t)N_NODES * 64 * 4); // 12.8 MB layer-1 inv denominators
    u16*  W1p   = (u16*)alloc((size_t)16 * H1 * 16);       // 128 KB
    u16*  p1w2p = (u16*)alloc((size_t)64 * H1 * 16);       // 512 KB
    u16*  w1f   = (u16*)alloc(2048 * 2);                   // mlp1 w1 frags
    u16*  w2f   = (u16*)alloc(4096 * 2);                   // mlp1 w2 frags
    u16*  w3f   = (u16*)alloc(512 * 2);                    // mlp2 w1 frags
    u16*  w4f   = (u16*)alloc(512 * 2);                    // mlp2 w2 frags
    u16*  w2hf  = (u16*)alloc(8192 * 2);                   // W2 hi frags (16 ks x 64 lanes x 8)
    u16*  w2lf  = (u16*)alloc(8192 * 2);                   // W2 lo (residual) frags
    int* src_cnt  = (int*)alloc(N_NODES * 4);
    int* dst_cnt  = (int*)alloc(N_NODES * 4);
    int* src_cur  = (int*)alloc(N_NODES * 4);
    int* dst_cur  = (int*)alloc(N_NODES * 4);
    int* partials = (int*)alloc(2 * NBLK * 4);
    int* src_off  = (int*)alloc((N_NODES + 1) * 4);
    int* dst_off  = (int*)alloc((N_NODES + 1) * 4);
    int* src_list = (int*)alloc((size_t)E_TOT * 4);        // dst-slot ids grouped by src
    int* deid     = (int*)alloc((size_t)E_TOT * 4);        // dst slot -> edge id
    int* dsrc     = (int*)alloc((size_t)E_TOT * 4);        // dst slot -> src node
    float* xh2  = (float*)alloc((size_t)N_NODES * NCLS * 4);
    float* agg2 = (float*)alloc((size_t)N_NODES * NCLS * 4);
    float* inv2 = (float*)alloc((size_t)N_NODES * NCLS * 4);

    const dim3 blk(256);
    const int EB = (E_TOT + 255) / 256;
    const int WB = (N_NODES * 64 + 255) / 256;
    const int GB16 = (N_NODES + 15) / 16;
    const dim3 gmm(512 / 128, M_PAD / 128);                 // (4, 391)
    const int MLPB = (E_TOT / 16 + 3) / 4;

    // ---- CSR build + weight/layout conversion ----
    hipMemsetAsync(src_cnt, 0, (char*)partials - (char*)src_cnt, stream);
    count_k<<<EB, blk, 0, stream>>>(ei, src_cnt, dst_cnt);
    scanA_k<<<2 * NBLK, blk, 0, stream>>>(src_cnt, dst_cnt, partials);
    scanB_k<<<1, 512, 0, stream>>>(partials);
    scanC_k<<<2 * NBLK, blk, 0, stream>>>(src_cnt, dst_cnt, partials, src_off, dst_off);
    fillD_k<<<8 * FBPR, blk, 0, stream>>>(ei, dst_off, dst_cur, deid, dsrc);
    fillS_k<<<8 * FBPR, blk, 0, stream>>>(dsrc, src_off, src_cur, src_list);
    conv_a_k<<<(16 * M_PAD + 255) / 256, blk, 0, stream>>>(x, xp, N_NODES, M_PAD, F_IN);
    conv_b_k<<<(16 * H1 + 255) / 256, blk, 0, stream>>>(W1, W1p, F_IN, H1);
    conv_b_k<<<(64 * H1 + 255) / 256, blk, 0, stream>>>(p1w2, p1w2p, H1, H1);
    wfrag_all_k<<<92, blk, 0, stream>>>(h1w1, h1w2, h2w1, h2w2, W2,
                                        w1f, w2f, w3f, w4f, w2hf, w2lf);

    // ---- layer 1 (reordered: edge MLPs + denominators BEFORE the x@W1 GEMM, so the
    //      GEMM epilogue can fuse the softmax scale + fp8 conversion and skip xb) ----
    edge_mlps_k<<<MLPB, blk, 0, stream>>>(kr, deid, w1f, w2f, h1b2, w3f, w4f, h2b2, ebd, ebd2);
    s1sum_k<<<WB, blk, 0, stream>>>(ebd, src_off, src_list, sinv1);
    mfma_gemm_k<1><<<gmm, blk, 0, stream>>>(xp, W1p, (u16*)xq, N_NODES, M_PAD, H1, F_IN,
                                            nullptr, nullptr, nullptr, nullptr,
                                            nullptr, nullptr, nullptr, sinv1);
    msg1_k<<<WB, blk, 0, stream>>>(ebd, xq, dsrc, dst_off, aggb);
    gemm_t1_k<<<dim3(8, (N_NODES + 63) / 64), blk, 0, stream>>>(ep, p1w1, t1p);   // overwrites xq region
    // fused: h = relu(aggb + b1 + alpha*leaky(t1@p1w2 + p1b2)); xh2 partials = h @ W2 (MFMA)
    mfma_gemm_k<3><<<gmm, blk, 0, stream>>>(t1p, p1w2p, nullptr, N_NODES, M_PAD, H1, H1,
                                            p1b2, aggb, b1, alpha, w2hf, w2lf, xh2p, nullptr);
    red4_k<<<(N_NODES * 4 + 255) / 256, blk, 0, stream>>>(xh2p, xh2);

    // ---- layer 2 ----
    s2sum_k<<<GB16, blk, 0, stream>>>(ebd2, src_off, src_list, inv2);
    msg2_k<<<GB16, blk, 0, stream>>>(ebd2, inv2, xh2, dsrc, dst_off, agg2);
    final_k<<<(N_NODES + 255) / 256, blk, 0, stream>>>(agg2, ep, p2w1, p2w2, p2b2, b2, alpha, out);
}

// Round 11
// 618.558 us; speedup vs baseline: 1.0032x; 1.0032x over previous
//
#include <hip/hip_runtime.h>
#include <math.h>

#define N_NODES 50000
#define M_PAD   50048    // N_NODES padded to multiple of 128 for MFMA tiles
#define N_EDGES 600000
#define E_TOT   650000   // N_EDGES + N_NODES (self loops appended)
#define F_IN    128
#define HID     64
#define HEADS   8
#define H1      512      // HEADS*HID
#define NCLS    16
#define NC      16
#define NCP     16
#define NBLK    ((N_NODES + 255) / 256)   // 196 scan blocks per array
#define FRNG    (N_NODES / 8)             // 6250 nodes per XCD range
#define FBPR    128                       // fill blocks per range
#define FPER    ((E_TOT + FBPR - 1) / FBPR)

typedef unsigned short u16;
typedef unsigned char  u8;
typedef __attribute__((ext_vector_type(8))) short short8;   // 8 bf16 = 4 VGPRs (MFMA A/B frag)
typedef __attribute__((ext_vector_type(4))) float f32x4;    // MFMA C/D frag
typedef __attribute__((ext_vector_type(2))) float f32x2;

__device__ __forceinline__ float bf2f(u16 h) {
    return __uint_as_float(((unsigned)h) << 16);
}
__device__ __forceinline__ u16 f2bf(float f) {
    unsigned u = __float_as_uint(f);
    u += 0x7fffu + ((u >> 16) & 1u);
    return (u16)(u >> 16);
}
__device__ __forceinline__ int edge_src(const int* __restrict__ ei, int e) {
    return (e < N_EDGES) ? ei[e] : (e - N_EDGES);
}
__device__ __forceinline__ int edge_dst(const int* __restrict__ ei, int e) {
    return (e < N_EDGES) ? ei[N_EDGES + e] : (e - N_EDGES);
}

// async global->LDS 16B copy: per-lane global src, wave-uniform LDS dest (+lane*16)
__device__ __forceinline__ void gload16(const void* g, void* l) {
    __builtin_amdgcn_global_load_lds(
        (const __attribute__((address_space(1))) unsigned int*)g,
        (__attribute__((address_space(3))) unsigned int*)l, 16, 0, 0);
}

// ---------------- CSR build ----------------
__global__ __launch_bounds__(256) void count_k(const int* __restrict__ ei,
                                               int* __restrict__ src_cnt, int* __restrict__ dst_cnt) {
    int e = blockIdx.x * 256 + threadIdx.x;
    if (e >= E_TOT) return;
    atomicAdd(&src_cnt[edge_src(ei, e)], 1);
    atomicAdd(&dst_cnt[edge_dst(ei, e)], 1);
}

// Phase A: per-block partial sums. grid = 2*NBLK (src blocks, then dst blocks).
__global__ __launch_bounds__(256) void scanA_k(const int* __restrict__ src_cnt,
                                               const int* __restrict__ dst_cnt,
                                               int* __restrict__ partials) {
    int pass = blockIdx.x >= NBLK;
    int b = blockIdx.x - pass * NBLK;
    const int* cnt = pass ? dst_cnt : src_cnt;
    int idx = b * 256 + threadIdx.x;
    int v = (idx < N_NODES) ? cnt[idx] : 0;
    __shared__ int red[4];
    #pragma unroll
    for (int off = 32; off; off >>= 1) v += __shfl_down(v, off, 64);
    if ((threadIdx.x & 63) == 0) red[threadIdx.x >> 6] = v;
    __syncthreads();
    if (threadIdx.x == 0) partials[blockIdx.x] = red[0] + red[1] + red[2] + red[3];
}

// Phase B: two independent exclusive scans of NBLK partials (src seg, dst seg), one block.
__global__ __launch_bounds__(512) void scanB_k(int* __restrict__ partials) {
    __shared__ int lds[512];
    int t = threadIdx.x;           // 512 threads: t<256 -> src segment, else dst
    int seg = t >> 8, i = t & 255;
    int v = (i < NBLK) ? partials[seg * NBLK + i] : 0;
    lds[t] = v;
    __syncthreads();
    for (int d = 1; d < 256; d <<= 1) {
        int x = (i >= d) ? lds[seg * 256 + i - d] : 0;
        __syncthreads();
        lds[t] += x;
        __syncthreads();
    }
    if (i < NBLK) partials[seg * NBLK + i] = lds[t] - v;   // exclusive
}

// Phase C: block-local exclusive scan + block offset -> off[]; off[N]=E_TOT constant.
__global__ __launch_bounds__(256) void scanC_k(const int* __restrict__ src_cnt,
                                               const int* __restrict__ dst_cnt,
                                               const int* __restrict__ partials,
                                               int* __restrict__ src_off, int* __restrict__ dst_off) {
    int pass = blockIdx.x >= NBLK;
    int b = blockIdx.x - pass * NBLK;
    const int* cnt = pass ? dst_cnt : src_cnt;
    int* off = pass ? dst_off : src_off;
    int base = partials[blockIdx.x];
    __shared__ int lds[256];
    int t = threadIdx.x;
    int idx = b * 256 + t;
    int v = (idx < N_NODES) ? cnt[idx] : 0;
    lds[t] = v;
    __syncthreads();
    for (int d = 1; d < 256; d <<= 1) {
        int x = (t >= d) ? lds[t - d] : 0;
        __syncthreads();
        lds[t] += x;
        __syncthreads();
    }
    if (idx < N_NODES) off[idx] = base + lds[t] - v;
    if (b == 0 && t == 0) off[N_NODES] = E_TOT;
}

// ---- fill pass D (XCD-range partitioned by dst): dsrc[slot]=src, deid[slot]=edge id.
__global__ __launch_bounds__(256) void fillD_k(const int* __restrict__ ei,
                                               const int* __restrict__ dst_off, int* __restrict__ dst_cur,
                                               int* __restrict__ deid, int* __restrict__ dsrc) {
    const int range = blockIdx.x & 7, slice = blockIdx.x >> 3;
    const int d0 = range * FRNG, d1 = d0 + FRNG;
    const int e0 = slice * FPER;
    const int e1 = (e0 + FPER < E_TOT) ? e0 + FPER : E_TOT;
    for (int e = e0 + threadIdx.x; e < e1; e += 256) {
        int d = edge_dst(ei, e);
        if (d < d0 || d >= d1) continue;
        int rd = dst_off[d] + atomicAdd(&dst_cur[d], 1);
        deid[rd] = e;
        dsrc[rd] = edge_src(ei, e);
    }
}

// ---- fill pass S (XCD-range partitioned by src): src_list[src slot] = dst-slot id.
__global__ __launch_bounds__(256) void fillS_k(const int* __restrict__ dsrc,
                                               const int* __restrict__ src_off, int* __restrict__ src_cur,
                                               int* __restrict__ src_list) {
    const int range = blockIdx.x & 7, slice = blockIdx.x >> 3;
    const int s0 = range * FRNG, s1 = s0 + FRNG;
    const int r0 = slice * FPER;
    const int r1 = (r0 + FPER < E_TOT) ? r0 + FPER : E_TOT;
    for (int rd = r0 + threadIdx.x; rd < r1; rd += 256) {
        int s = dsrc[rd];
        if (s < s0 || s >= s1) continue;
        src_list[src_off[s] + atomicAdd(&src_cur[s], 1)] = rd;
    }
}

// ---------------- layout converters ----------------
// f32 [M][K] row-major -> bf16 fragment-major Ap[K/8][Mp][8]; pad rows zeroed
__global__ __launch_bounds__(256) void conv_a_k(const float* __restrict__ A, u16* __restrict__ Ap,
                                                int M, int Mp, int K) {
    int i = blockIdx.x * 256 + threadIdx.x;
    int total = (K >> 3) * Mp;
    if (i >= total) return;
    int r = i % Mp;
    int kb = i / Mp;
    u16* o = Ap + (size_t)i * 8;
    u16 tmp[8];
    if (r < M) {
        const float* a = A + (size_t)r * K + kb * 8;
        #pragma unroll
        for (int j = 0; j < 8; ++j) tmp[j] = f2bf(a[j]);
    } else {
        #pragma unroll
        for (int j = 0; j < 8; ++j) tmp[j] = 0;
    }
    *(ushort4*)o = *(ushort4*)tmp;
    *(ushort4*)(o + 4) = *(ushort4*)(tmp + 4);
}

// f32 [K][N] row-major -> bf16 fragment-major Bp[K/8][N][8] (Bp[kb][n][j] = B[kb*8+j][n])
__global__ __launch_bounds__(256) void conv_b_k(const float* __restrict__ B, u16* __restrict__ Bp,
                                                int K, int N) {
    int i = blockIdx.x * 256 + threadIdx.x;
    int total = (K >> 3) * N;
    if (i >= total) return;
    int n = i % N;
    int kb = i / N;
    u16 tmp[8];
    #pragma unroll
    for (int j = 0; j < 8; ++j) tmp[j] = f2bf(B[(size_t)(kb * 8 + j) * N + n]);
    u16* o = Bp + (size_t)i * 8;
    *(ushort4*)o = *(ushort4*)tmp;
    *(ushort4*)(o + 4) = *(ushort4*)(tmp + 4);
}

// per-lane B-frag layout tables for MFMA 16x16x32
__device__ __forceinline__ void wfrag_one(const float* W, u16* o, int i, int K, int N) {
    int j = i & 7, lane = (i >> 3) & 63, rest = i >> 9;
    int nt = rest % (N / 16), ks = rest / (N / 16);
    int lm = lane & 15, quad = lane >> 4;
    int k = ks * 32 + quad * 8 + j, n = nt * 16 + lm;
    o[i] = (k < K) ? f2bf(W[(size_t)k * N + n]) : (u16)0;
}
// residual table: lo = bf16(W - bf16(W)) so hi+lo MFMA pair == f32-precision W
__device__ __forceinline__ void wfrag_res(const float* W, u16* o, int i, int K, int N) {
    int j = i & 7, lane = (i >> 3) & 63, rest = i >> 9;
    int nt = rest % (N / 16), ks = rest / (N / 16);
    int lm = lane & 15, quad = lane >> 4;
    int k = ks * 32 + quad * 8 + j, n = nt * 16 + lm;
    float w = (k < K) ? W[(size_t)k * N + n] : 0.f;
    o[i] = f2bf(w - bf2f(f2bf(w)));
}
__global__ __launch_bounds__(256) void wfrag_all_k(
    const float* __restrict__ h1w1, const float* __restrict__ h1w2,
    const float* __restrict__ h2w1, const float* __restrict__ h2w2,
    const float* __restrict__ W2,
    u16* __restrict__ w1f, u16* __restrict__ w2f,
    u16* __restrict__ w3f, u16* __restrict__ w4f,
    u16* __restrict__ w2hf, u16* __restrict__ w2lf) {
    int i = blockIdx.x * 256 + threadIdx.x;   // total 7168 + 2*8192 = 23552
    if (i < 2048)       wfrag_one(h1w1, w1f, i, 16, 64);          // Kpad 32, N 64
    else if (i < 6144)  wfrag_one(h1w2, w2f, i - 2048, 64, 64);   // Kpad 64, N 64
    else if (i < 6656)  wfrag_one(h2w1, w3f, i - 6144, 16, 16);
    else if (i < 7168)  wfrag_one(h2w2, w4f, i - 6656, 16, 16);
    else if (i < 15360) wfrag_one(W2, w2hf, i - 7168, 512, 16);   // W2 hi frags (16 ks chunks)
    else if (i < 23552) wfrag_res(W2, w2lf, i - 15360, 512, 16);  // W2 lo (residual) frags
}

// ---------------- MFMA GEMM: frag-major operands, 128x128 tile, 4 waves ----------------
// K-loop (round-9 proven): A triple-buffered in LDS (3x8KB) with counted-vmcnt depth-2
// prefetch; B (L2-hot) in REGISTERS with depth-1 ping-pong; B(ts) issued before A(ts+1)
// so B-waits never retire the A prefetch. LDS 32KB (epilogue Tf aliases the A buffers;
// Hs aliases Tf's first half) and __launch_bounds__(256,4) -> 4 blocks/CU.
// EPI==1 (x @ W1 path): h1 = acc is NOT stored as bf16; the epilogue applies the
//   ex-s1inv phase-2 chain directly: y = bf2f(f2bf(acc)) * sinv[row][ch&63] -> fp8
//   and writes the 512B-stride fp8 gather table. Requires sinv precomputed (s1sum_k).
// EPI==3 (t1 @ p1w2 path): h = relu(extra + bias2 + alpha*leaky(acc + bias, 0.01)) is
//   NOT stored; bf16(h) goes through the XOR-swizzled Hs tile and the MATRIX pipe:
//   xh2 partial = h @ (W2hi+W2lo), W2 frags loaded per-kc from L2-hot tables.
template<int EPI>
__global__ __launch_bounds__(256, 4) void mfma_gemm_k(
    const u16* __restrict__ Ap, const u16* __restrict__ Bp, u16* __restrict__ C,
    int M, int Mp, int Nn, int K,
    const float* __restrict__ bias, const u16* __restrict__ extra,
    const float* __restrict__ bias2, const float* __restrict__ alpha_p,
    const u16* __restrict__ w2hf, const u16* __restrict__ w2lf,
    float* __restrict__ xh2p, const float* __restrict__ sinvp)
{
    __shared__ __align__(16) char LSD[32768];   // loop: 3x8KB A bufs; epilogue: Tf 32KB
    const int t = threadIdx.x;
    const int wave = t >> 6, lane = t & 63;
    const int wm = (wave >> 1) * 64, wn = (wave & 1) * 64;
    const int lm = lane & 15, quad = lane >> 4;

    // bijective XCD-chunk swizzle (m204 formula); dispatch->XCD assumed bid%8.
    const int nwg = (int)(gridDim.y << 2);
    const int bid = (int)(blockIdx.y * 4 + blockIdx.x);
    const int qq = nwg >> 3, rr8 = nwg & 7;
    const int xcd = bid & 7, idx = bid >> 3;
    const int wg = (xcd < rr8 ? xcd * (qq + 1) : rr8 * (qq + 1) + (xcd - rr8) * qq) + idx;
    const int bn = (wg & 3) * 128;
    const int bm = (wg >> 2) * 128;

    const char* Ab = (const char*)Ap;
    size_t cbase[4];
    #pragma unroll
    for (int nj = 0; nj < 4; ++nj) cbase[nj] = (size_t)(bn + wn + nj * 16 + lm) * 8;

    f32x4 acc[4][4] = {};
    const int NT = K >> 5;   // K-steps of 32 (4 or 16, even)

    // stage K-step ts's A tile (8 KB) into buffer b: 2 gload16 per wave
    auto stageA = [&](int b, int ts) {
        const int kb0 = ts * 4;
        #pragma unroll
        for (int h = 0; h < 2; ++h) {
            const int ob = h * 4096 + wave * 1024;     // wave-uniform LDS byte base
            const int kb = kb0 + (ob >> 11);           // which k/8 chunk
            const int rem = (ob & 1024) + lane * 16;   // byte offset inside 2 KB chunk
            gload16(Ab + ((size_t)kb * Mp + bm) * 16 + rem, LSD + b * 8192 + ob);
        }
    };
    // B fragments for K-step ts: 4 x 16B per lane, straight from L2
    auto loadB = [&](short8 (&bf)[4], int ts) {
        const u16* Bq = Bp + (size_t)(ts * 4 + quad) * Nn * 8;
        #pragma unroll
        for (int nj = 0; nj < 4; ++nj) bf[nj] = *(const short8*)(Bq + cbase[nj]);
    };
    auto compute = [&](int cb, short8 (&bf)[4]) {
        const u16* As = (const u16*)(LSD + cb * 8192);
        short8 af[4];
        #pragma unroll
        for (int mi = 0; mi < 4; ++mi)
            af[mi] = *(const short8*)(As + quad * 1024 + (wm + mi * 16 + lm) * 8);
        #pragma unroll
        for (int mi = 0; mi < 4; ++mi)
            #pragma unroll
            for (int nj = 0; nj < 4; ++nj)
                acc[mi][nj] = __builtin_amdgcn_mfma_f32_16x16x32_bf16(af[mi], bf[nj], acc[mi][nj], 0, 0, 0);
    };

    short8 b0[4], b1[4];
    stageA(0, 0);        // A0 (oldest)
    loadB(b0, 0);        // B0 before A1: B-waits never retire the A prefetch
    stageA(1, 1);        // A1
    #pragma unroll 1
    for (int ts = 0; ts < NT - 2; ts += 2) {
        asm volatile("s_waitcnt vmcnt(6)" ::: "memory");   // A(ts) landed (mine)
        __builtin_amdgcn_sched_barrier(0);
        __builtin_amdgcn_s_barrier();                      // => everyone's A(ts) landed
        loadB(b1, ts + 1);
        stageA((ts + 2) % 3, ts + 2);
        compute(ts % 3, b0);
        asm volatile("s_waitcnt vmcnt(6)" ::: "memory");   // A(ts+1) landed
        __builtin_amdgcn_sched_barrier(0);
        __builtin_amdgcn_s_barrier();
        loadB(b0, ts + 2);
        stageA((ts + 3) % 3, ts + 3);
        compute((ts + 1) % 3, b1);
    }
    // ts = NT-2
    asm volatile("s_waitcnt vmcnt(6)" ::: "memory");
    __builtin_amdgcn_sched_barrier(0);
    __builtin_amdgcn_s_barrier();
    loadB(b1, NT - 1);
    compute((NT - 2) % 3, b0);
    // ts = NT-1
    asm volatile("s_waitcnt vmcnt(4)" ::: "memory");       // A(NT-1) landed
    __builtin_amdgcn_sched_barrier(0);
    __builtin_amdgcn_s_barrier();
    compute((NT - 1) % 3, b1);
    __syncthreads();            // full rendezvous before epilogue reuses LSD

    // ---- epilogue: acc -> 64x128 f32 LDS tile Tf (XOR swizzle) -> consume ----
    float* Tf = (float*)LSD;
    const float alpha = (EPI == 3) ? *alpha_p : 0.f;
    #pragma unroll
    for (int pass = 0; pass < 2; ++pass) {
        if ((wave >> 1) == pass) {
            #pragma unroll
            for (int mi = 0; mi < 4; ++mi)
                #pragma unroll
                for (int r4 = 0; r4 < 4; ++r4) {
                    const int lr = mi * 16 + quad * 4 + r4;
                    const int sw = (lr & 7) << 2;
                    #pragma unroll
                    for (int nj = 0; nj < 4; ++nj)
                        Tf[lr * 128 + ((wn + nj * 16 + lm) ^ sw)] = acc[mi][nj][r4];
                }
        }
        __syncthreads();
        if (EPI == 1) {
            // fused ex-s1inv phase 2: y = bf16round(acc) * sinv -> fp8 table (512B rows)
            const int lrow = t & 63, chunk = t >> 6;
            const int col0 = chunk * 32;
            const int rr = bm + pass * 64 + lrow;
            if (rr < M) {
                const int sw = (lrow & 7) << 2;
                float v[32];
                #pragma unroll
                for (int j4 = 0; j4 < 8; ++j4) {
                    float4 f = *(const float4*)&Tf[lrow * 128 + ((col0 + j4 * 4) ^ sw)];
                    v[j4 * 4] = f.x; v[j4 * 4 + 1] = f.y; v[j4 * 4 + 2] = f.z; v[j4 * 4 + 3] = f.w;
                }
                const int gc0 = bn + col0;
                const float* sv = sinvp + (size_t)rr * 64 + (gc0 & 63);  // 32 consecutive
                int pw[8];
                #pragma unroll
                for (int g = 0; g < 8; ++g) {
                    float y0 = bf2f(f2bf(v[g * 4 + 0])) * sv[g * 4 + 0];
                    float y1 = bf2f(f2bf(v[g * 4 + 1])) * sv[g * 4 + 1];
                    float y2 = bf2f(f2bf(v[g * 4 + 2])) * sv[g * 4 + 2];
                    float y3 = bf2f(f2bf(v[g * 4 + 3])) * sv[g * 4 + 3];
                    int p0 = __builtin_amdgcn_cvt_pk_fp8_f32(y0, y1, 0, false);
                    pw[g] = __builtin_amdgcn_cvt_pk_fp8_f32(y2, y3, p0, true);
                }
                u8* dst = (u8*)C + (size_t)rr * 512 + gc0;
                *(uint4*)dst        = make_uint4(pw[0], pw[1], pw[2], pw[3]);
                *(uint4*)(dst + 16) = make_uint4(pw[4], pw[5], pw[6], pw[7]);
            }
        } else {
            u8* HsB = (u8*)LSD;                  // aliases Tf's first 16KB (barrier-guarded)
            const int row = wave * 16 + lm;      // 0..63 (one h-row per lane)
            const int col0 = quad * 32;
            const int rr = bm + pass * 64 + row;
            const int gc0 = bn + col0;
            u16 hpk[32];
            if (rr < M) {
                const int sw = (row & 7) << 2;
                const u16* ex = extra + (size_t)rr * Nn + gc0;
                #pragma unroll
                for (int g = 0; g < 4; ++g) {
                    float4 f0 = *(const float4*)&Tf[row * 128 + ((col0 + g * 8) ^ sw)];
                    float4 f1 = *(const float4*)&Tf[row * 128 + ((col0 + g * 8 + 4) ^ sw)];
                    float vv8[8] = {f0.x, f0.y, f0.z, f0.w, f1.x, f1.y, f1.z, f1.w};
                    short8 e8 = *(const short8*)(ex + g * 8);
                    #pragma unroll
                    for (int j = 0; j < 8; ++j) {
                        const int cj = g * 8 + j;
                        float vv = vv8[j] + bias[gc0 + cj];
                        vv = vv > 0.f ? vv : 0.01f * vv;
                        float o = bf2f((u16)e8[j]) + bias2[gc0 + cj] + alpha * vv;
                        o = fmaxf(o, 0.f);
                        hpk[cj] = f2bf(o);      // identical to the old hb bf16 value
                    }
                }
            } else {
                #pragma unroll
                for (int j = 0; j < 32; ++j) hpk[j] = 0;
            }
            __syncthreads();                     // all Tf reads done before Hs overwrite
            // bf16 h row -> Hs (XOR-swizzled 16B slots: bank-clean write AND read)
            #pragma unroll
            for (int g = 0; g < 4; ++g) {
                const int ba = (row * 256 + quad * 64 + g * 16) ^ ((row & 7) << 4);
                *(short8*)(HsB + ba) = *(const short8*)&hpk[g * 8];
            }
            __syncthreads();
            // A-frags from Hs; xh2 partial = h @ (W2hi + W2lo) on the matrix pipe.
            // W2 hi/lo frags loaded per-kc from L2-hot tables (transient regs).
            f32x4 axh = {};
            const int ksb = bn >> 5;
            #pragma unroll
            for (int kc = 0; kc < 4; ++kc) {
                const int ba = (row * 256 + kc * 64 + quad * 16) ^ ((row & 7) << 4);
                short8 ha = *(const short8*)(HsB + ba);
                short8 wh = *(const short8*)(w2hf + ((size_t)(ksb + kc) * 64 + lane) * 8);
                short8 wl = *(const short8*)(w2lf + ((size_t)(ksb + kc) * 64 + lane) * 8);
                axh = __builtin_amdgcn_mfma_f32_16x16x32_bf16(ha, wh, axh, 0, 0, 0);
                axh = __builtin_amdgcn_mfma_f32_16x16x32_bf16(ha, wl, axh, 0, 0, 0);
            }
            // C/D layout: col = lane&15, row = quad*4 + reg
            #pragma unroll
            for (int r = 0; r < 4; ++r) {
                const int prow = bm + pass * 64 + wave * 16 + quad * 4 + r;
                if (prow < M)
                    xh2p[((size_t)(bn >> 7) * M_PAD + prow) * 16 + lm] = axh[r];
            }
        }
        __syncthreads();
    }
}

// ---------------- z2 = (sum of 4 xh2 partials) * inv2  (layer-2 fused gather table) ----------------
__global__ __launch_bounds__(256) void red4z_k(const float* __restrict__ xh2p,
                                               const float* __restrict__ inv2,
                                               float* __restrict__ z2) {
    int i = blockIdx.x * 256 + threadIdx.x;     // float4 index over [N_NODES][16]
    if (i >= N_NODES * 4) return;
    const float4* P = (const float4*)xh2p;
    const size_t S = (size_t)M_PAD * 4;         // float4s per slice
    float4 a = P[i], b = P[S + i], c = P[2 * S + i], d = P[3 * S + i];
    float4 iv = ((const float4*)inv2)[i];
    float4 r;
    r.x = ((a.x + b.x) + (c.x + d.x)) * iv.x;
    r.y = ((a.y + b.y) + (c.y + d.y)) * iv.y;
    r.z = ((a.z + b.z) + (c.z + d.z)) * iv.z;
    r.w = ((a.w + b.w) + (c.w + d.w)) * iv.w;
    ((float4*)z2)[i] = r;
}

// ---------------- t1 = leaky(ep @ p1w1, 0.2), K=16, written in frag-major Ap layout ----------------
__global__ __launch_bounds__(256) void gemm_t1_k(
    const float* __restrict__ ep, const float* __restrict__ W, u16* __restrict__ t1p)
{
    __shared__ float Bs[16][64];
    const int bm = blockIdx.y * 64, bn = blockIdx.x * 64;
    const int t = threadIdx.x;
    const int tx = t & 15, ty = t >> 4;
    *(float4*)&Bs[t >> 4][(t & 15) * 4] = *(const float4*)&W[(size_t)(t >> 4) * H1 + bn + (t & 15) * 4];
    __syncthreads();
    const int r0 = bm + ty * 4;
    const int c0 = bn + tx * 4;
    for (int i = 0; i < 4; ++i) {
        int r = r0 + i;
        if (r >= N_NODES) continue;
        float av[16];
        #pragma unroll
        for (int j4 = 0; j4 < 16; j4 += 4) {
            float4 v = *(const float4*)(ep + (size_t)r * NCP + j4);
            av[j4] = v.x; av[j4 + 1] = v.y; av[j4 + 2] = v.z; av[j4 + 3] = v.w;
        }
        u16 pk[4];
        #pragma unroll
        for (int q = 0; q < 4; ++q) {
            float s = 0.f;
            #pragma unroll
            for (int k = 0; k < 16; ++k) s = fmaf(av[k], Bs[k][tx * 4 + q], s);
            s = s > 0.f ? s : 0.2f * s;
            pk[q] = f2bf(s);
        }
        u16* o = t1p + ((size_t)(c0 >> 3) * M_PAD + r) * 8 + (c0 & 7);
        *(ushort4*)o = *(ushort4*)pk;
    }
}

// ---------------- fused MFMA edge MLPs, SLOT-ordered: gather kr via deid, ----------------
// ---------------- write ebd / ebd2 fully sequentially (no scatter)        ----------------
#define TSTR 72   // LDS tile row stride in bf16 elems (144 B: 16B-aligned frag reads, <=2-way banks)
__global__ __launch_bounds__(256) void edge_mlps_k(
    const float* __restrict__ kr, const int* __restrict__ deid,
    const u16* __restrict__ w1f, const u16* __restrict__ w2f, const float* __restrict__ b2a,
    const u16* __restrict__ w3f, const u16* __restrict__ w4f, const float* __restrict__ b2b,
    u16* __restrict__ ebd, u16* __restrict__ ebd2)
{
    __shared__ __align__(16) u16 T[4][16 * TSTR];
    const int t = threadIdx.x, wv = t >> 6, lane = t & 63;
    const int lm = lane & 15, quad = lane >> 4;
    const int tile = blockIdx.x * 4 + wv;
    const int s0 = tile * 16;          // dst-slot base (16 consecutive slots)
    if (s0 >= E_TOT) return;
    u16* Tw = T[wv];

    // weight fragments -> VGPRs (per-lane)
    short8 W1[4], W2[2][4];
    #pragma unroll
    for (int nt = 0; nt < 4; ++nt) W1[nt] = *(const short8*)(w1f + ((size_t)nt * 64 + lane) * 8);
    #pragma unroll
    for (int ks = 0; ks < 2; ++ks)
        #pragma unroll
        for (int nt = 0; nt < 4; ++nt)
            W2[ks][nt] = *(const short8*)(w2f + (((size_t)ks * 4 + nt) * 64 + lane) * 8);
    short8 W3 = *(const short8*)(w3f + (size_t)lane * 8);
    short8 W4 = *(const short8*)(w4f + (size_t)lane * 8);
    float b2av[4];
    #pragma unroll
    for (int nt = 0; nt < 4; ++nt) b2av[nt] = b2a[nt * 16 + lm];
    float b2bv = b2b[lm];

    // A-frag: slot row m = s0+lm -> edge e = deid[s0+lm]; k = quad*8+j (K=16 padded to 32)
    const int e = deid[s0 + lm];
    short8 af = {};
    if (quad < 2) {
        const float* kp = kr + (size_t)e * NC + quad * 8;
        float4 v0 = *(const float4*)kp;
        float4 v1 = *(const float4*)(kp + 4);
        u16 tmp[8] = {f2bf(v0.x), f2bf(v0.y), f2bf(v0.z), f2bf(v0.w),
                      f2bf(v1.x), f2bf(v1.y), f2bf(v1.z), f2bf(v1.w)};
        af = *(const short8*)tmp;
    }

    // ---- MLP1 layer 1: [16 slots x 64] = kr @ w1, leaky 0.2 ----
    f32x4 a1[4] = {};
    #pragma unroll
    for (int nt = 0; nt < 4; ++nt)
        a1[nt] = __builtin_amdgcn_mfma_f32_16x16x32_bf16(af, W1[nt], a1[nt], 0, 0, 0);
    #pragma unroll
    for (int nt = 0; nt < 4; ++nt)
        #pragma unroll
        for (int r = 0; r < 4; ++r) {
            float v = a1[nt][r];
            v = v > 0.f ? v : 0.2f * v;
            Tw[(quad * 4 + r) * TSTR + nt * 16 + lm] = f2bf(v);
        }
    __builtin_amdgcn_s_waitcnt(0);   // drain LDS writes before same-wave reads

    // ---- MLP1 layer 2: K=64 from LDS tile ----
    short8 a2[2];
    #pragma unroll
    for (int ks = 0; ks < 2; ++ks)
        a2[ks] = *(const short8*)&Tw[lm * TSTR + ks * 32 + quad * 8];
    f32x4 c2[4] = {};
    #pragma unroll
    for (int nt = 0; nt < 4; ++nt)
        #pragma unroll
        for (int ks = 0; ks < 2; ++ks)
            c2[nt] = __builtin_amdgcn_mfma_f32_16x16x32_bf16(a2[ks], W2[ks][nt], c2[nt], 0, 0, 0);
    // epilogue: + b2, exp -> LDS
    #pragma unroll
    for (int nt = 0; nt < 4; ++nt)
        #pragma unroll
        for (int r = 0; r < 4; ++r)
            Tw[(quad * 4 + r) * TSTR + nt * 16 + lm] = f2bf(__expf(c2[nt][r] + b2av[nt]));
    __builtin_amdgcn_s_waitcnt(0);
    // repack: rows are consecutive slots -> 2 KB fully-contiguous store per wave
    #pragma unroll
    for (int p = 0; p < 2; ++p) {
        int c = p * 64 + lane;
        int row = c >> 3, off = (c & 7) * 8;
        short8 v = *(const short8*)&Tw[row * TSTR + off];
        *(short8*)(ebd + (size_t)(s0 + row) * HID + off) = v;
    }

    // ---- MLP2 (16->16->16), reuses kr A-frag ----
    f32x4 b1 = __builtin_amdgcn_mfma_f32_16x16x32_bf16(af, W3, (f32x4){}, 0, 0, 0);
    __builtin_amdgcn_s_waitcnt(0);   // eb repack reads done before overwrite
    #pragma unroll
    for (int r = 0; r < 4; ++r) {
        float v = b1[r];
        v = v > 0.f ? v : 0.2f * v;
        Tw[(quad * 4 + r) * TSTR + lm] = f2bf(v);
    }
    __builtin_amdgcn_s_waitcnt(0);
    // A-frag: cols 16..31 hold stale finite values, but W4 is zero there -> no effect
    short8 a3 = *(const short8*)&Tw[lm * TSTR + quad * 8];
    f32x4 c3 = __builtin_amdgcn_mfma_f32_16x16x32_bf16(a3, W4, (f32x4){}, 0, 0, 0);
    #pragma unroll
    for (int r = 0; r < 4; ++r)
        Tw[(quad * 4 + r) * TSTR + lm] = f2bf(__expf(c3[r] + b2bv));
    __builtin_amdgcn_s_waitcnt(0);
    if (lane < 32) {
        int row = lane >> 1, off = (lane & 1) * 8;
        short8 v = *(const short8*)&Tw[row * TSTR + off];
        *(short8*)(ebd2 + (size_t)(s0 + row) * NCLS + off) = v;   // 512 B contiguous per wave
    }
}

// ---------------- layer-1 softmax denominator only (wave per src) -> sinv[N][64] ----------------
__global__ __launch_bounds__(256) void s1sum_k(
    const u16* __restrict__ ebd, const int* __restrict__ src_off, const int* __restrict__ src_list,
    float* __restrict__ sinv)
{
    int gid = blockIdx.x * 256 + threadIdx.x;
    int wid = gid >> 6, lane = gid & 63;
    if (wid >= N_NODES) return;
    int o0 = src_off[wid], o1 = src_off[wid + 1];
    float s0 = 0.f, s1 = 0.f, s2 = 0.f, s3 = 0.f;
    int i = o0;
    for (; i + 3 < o1; i += 4) {
        int l0 = src_list[i], l1 = src_list[i + 1], l2 = src_list[i + 2], l3 = src_list[i + 3];
        s0 += bf2f(ebd[(size_t)l0 * HID + lane]);
        s1 += bf2f(ebd[(size_t)l1 * HID + lane]);
        s2 += bf2f(ebd[(size_t)l2 * HID + lane]);
        s3 += bf2f(ebd[(size_t)l3 * HID + lane]);
    }
    for (; i < o1; ++i) {
        int sl = src_list[i];
        s0 += bf2f(ebd[(size_t)sl * HID + lane]);
    }
    sinv[(size_t)wid * 64 + lane] = 1.f / (((s0 + s1) + (s2 + s3)) + 1e-16f);
}

// ---------------- message pass 1: wave per dst, sequential slots, fp8 gather, unroll 4 ----------------
__global__ __launch_bounds__(256) void msg1_k(
    const u16* __restrict__ ebd, const u8* __restrict__ xq,
    const int* __restrict__ dsrc, const int* __restrict__ dst_off,
    u16* __restrict__ aggb)
{
    int gid = blockIdx.x * 256 + threadIdx.x;
    int wid = gid >> 6, lane = gid & 63;
    if (wid >= N_NODES) return;
    int o0 = dst_off[wid], o1 = dst_off[wid + 1];
    const int a_off = (lane & 7) * 8;     // alpha channel block (ch = lane*8+j mod 64)
    float acc[8] = {};
    int i = o0;
    for (; i + 3 < o1; i += 4) {
        int s0 = __builtin_nontemporal_load(dsrc + i);
        int s1 = __builtin_nontemporal_load(dsrc + i + 1);
        int s2 = __builtin_nontemporal_load(dsrc + i + 2);
        int s3 = __builtin_nontemporal_load(dsrc + i + 3);
        short8 a0 = __builtin_nontemporal_load((const short8*)(ebd + (size_t)i * HID + a_off));
        short8 a1 = __builtin_nontemporal_load((const short8*)(ebd + (size_t)(i + 1) * HID + a_off));
        short8 a2 = __builtin_nontemporal_load((const short8*)(ebd + (size_t)(i + 2) * HID + a_off));
        short8 a3 = __builtin_nontemporal_load((const short8*)(ebd + (size_t)(i + 3) * HID + a_off));
        uint2 q0 = *(const uint2*)(xq + (size_t)s0 * 512 + lane * 8);
        uint2 q1 = *(const uint2*)(xq + (size_t)s1 * 512 + lane * 8);
        uint2 q2 = *(const uint2*)(xq + (size_t)s2 * 512 + lane * 8);
        uint2 q3 = *(const uint2*)(xq + (size_t)s3 * 512 + lane * 8);
        const uint2 qs[4] = {q0, q1, q2, q3};
        const short8 as[4] = {a0, a1, a2, a3};
        #pragma unroll
        for (int u = 0; u < 4; ++u) {
            f32x2 d0 = __builtin_amdgcn_cvt_pk_f32_fp8((int)qs[u].x, false);
            f32x2 d1 = __builtin_amdgcn_cvt_pk_f32_fp8((int)qs[u].x, true);
            f32x2 d2 = __builtin_amdgcn_cvt_pk_f32_fp8((int)qs[u].y, false);
            f32x2 d3 = __builtin_amdgcn_cvt_pk_f32_fp8((int)qs[u].y, true);
            float xv[8] = {d0.x, d0.y, d1.x, d1.y, d2.x, d2.y, d3.x, d3.y};
            #pragma unroll
            for (int j = 0; j < 8; ++j)
                acc[j] = fmaf(bf2f((u16)as[u][j]), xv[j], acc[j]);
        }
    }
    for (; i < o1; ++i) {
        int s = __builtin_nontemporal_load(dsrc + i);
        short8 a8 = __builtin_nontemporal_load((const short8*)(ebd + (size_t)i * HID + a_off));
        uint2 q = *(const uint2*)(xq + (size_t)s * 512 + lane * 8);
        f32x2 d0 = __builtin_amdgcn_cvt_pk_f32_fp8((int)q.x, false);
        f32x2 d1 = __builtin_amdgcn_cvt_pk_f32_fp8((int)q.x, true);
        f32x2 d2 = __builtin_amdgcn_cvt_pk_f32_fp8((int)q.y, false);
        f32x2 d3 = __builtin_amdgcn_cvt_pk_f32_fp8((int)q.y, true);
        float xv[8] = {d0.x, d0.y, d1.x, d1.y, d2.x, d2.y, d3.x, d3.y};
        #pragma unroll
        for (int j = 0; j < 8; ++j)
            acc[j] = fmaf(bf2f((u16)a8[j]), xv[j], acc[j]);
    }
    u16 pk[8];
    #pragma unroll
    for (int j = 0; j < 8; ++j) pk[j] = f2bf(acc[j]);
    __builtin_nontemporal_store(*(const short8*)pk, (short8*)(aggb + (size_t)wid * H1 + lane * 8));
}

// ---------------- inverse denominator, layer 2 (16 threads per src) ----------------
__global__ __launch_bounds__(256) void s2sum_k(
    const u16* __restrict__ ebd2, const int* __restrict__ src_off, const int* __restrict__ src_list,
    float* __restrict__ inv2)
{
    int t = threadIdx.x;
    int g = blockIdx.x * 16 + (t >> 4), c = t & 15;
    if (g >= N_NODES) return;
    int o0 = src_off[g], o1 = src_off[g + 1];
    float sum = 0.f;
    for (int i = o0; i < o1; ++i) {
        int sl = src_list[i];
        sum += bf2f(ebd2[(size_t)sl * NCLS + c]);
    }
    inv2[(size_t)g * NCLS + c] = 1.f / (sum + 1e-16f);
}

// ---------------- message pass 2 (16 threads per dst): acc += ebd2[i] * z2[src] ----------------
// z2 = inv2*xh2 precomputed per node (3.2 MB, ~L2-resident) -> ONE random gather per edge
__global__ __launch_bounds__(256) void msg2_k(
    const u16* __restrict__ ebd2, const float* __restrict__ z2,
    const int* __restrict__ dsrc, const int* __restrict__ dst_off,
    float* __restrict__ agg2)
{
    int t = threadIdx.x;
    int g = blockIdx.x * 16 + (t >> 4), c = t & 15;
    if (g >= N_NODES) return;
    int o0 = dst_off[g], o1 = dst_off[g + 1];
    float acc = 0.f;
    for (int i = o0; i < o1; ++i) {
        int s = dsrc[i];
        float a = bf2f(ebd2[(size_t)i * NCLS + c]);
        acc = fmaf(a, z2[(size_t)s * NCLS + c], acc);
    }
    agg2[(size_t)g * NCLS + c] = acc;
}

// ---------------- final: o = agg2 + bias2 + alpha*p2; log_softmax ----------------
__global__ __launch_bounds__(256) void final_k(
    const float* __restrict__ agg2, const float* __restrict__ ep,
    const float* __restrict__ pw1, const float* __restrict__ pw2,
    const float* __restrict__ pb2, const float* __restrict__ bias,
    const float* __restrict__ alpha_p, float* __restrict__ out)
{
    __shared__ float s1w[256], s2w[256], sb[16], sbias[16];
    const int t = threadIdx.x;
    s1w[t] = pw1[t];
    s2w[t] = pw2[t];
    if (t < 16) { sb[t] = pb2[t]; sbias[t] = bias[t]; }
    __syncthreads();
    const int v = blockIdx.x * 256 + t;
    if (v >= N_NODES) return;
    float alpha = *alpha_p;
    float e_[16];
    #pragma unroll
    for (int j4 = 0; j4 < 16; j4 += 4) {
        float4 vv = *(const float4*)(ep + (size_t)v * 16 + j4);
        e_[j4] = vv.x; e_[j4 + 1] = vv.y; e_[j4 + 2] = vv.z; e_[j4 + 3] = vv.w;
    }
    float t2[16];
    #pragma unroll
    for (int c = 0; c < 16; ++c) {
        float s = 0.f;
        #pragma unroll
        for (int j = 0; j < 16; ++j) s = fmaf(e_[j], s1w[j * 16 + c], s);
        t2[c] = s > 0.f ? s : 0.2f * s;
    }
    float o[16];
    #pragma unroll
    for (int c4 = 0; c4 < 16; c4 += 4) {
        float4 ag = *(const float4*)(agg2 + (size_t)v * 16 + c4);
        float agv[4] = {ag.x, ag.y, ag.z, ag.w};
        #pragma unroll
        for (int q = 0; q < 4; ++q) {
            int c = c4 + q;
            float p = sb[c];
            #pragma unroll
            for (int j = 0; j < 16; ++j) p = fmaf(t2[j], s2w[j * 16 + c], p);
            p = p > 0.f ? p : 0.01f * p;
            o[c] = agv[q] + sbias[c] + alpha * p;
        }
    }
    float mx = o[0];
    #pragma unroll
    for (int c = 1; c < 16; ++c) mx = fmaxf(mx, o[c]);
    float se = 0.f;
    #pragma unroll
    for (int c = 0; c < 16; ++c) se += expf(o[c] - mx);
    float lse = mx + logf(se);
    #pragma unroll
    for (int c4 = 0; c4 < 16; c4 += 4)
        *(float4*)(out + (size_t)v * 16 + c4) =
            make_float4(o[c4] - lse, o[c4 + 1] - lse, o[c4 + 2] - lse, o[c4 + 3] - lse);
}

extern "C" void kernel_launch(void* const* d_in, const int* in_sizes, int n_in,
                              void* d_out, int out_size, void* d_ws, size_t ws_size,
                              hipStream_t stream) {
    const float* x    = (const float*)d_in[0];
    const int*   ei   = (const int*)d_in[1];
    const float* alpha= (const float*)d_in[2];
    const float* kr   = (const float*)d_in[3];
    const float* ep   = (const float*)d_in[4];
    const float* W1   = (const float*)d_in[5];
    const float* h1w1 = (const float*)d_in[6];
    const float* h1w2 = (const float*)d_in[7];
    const float* h1b2 = (const float*)d_in[8];
    const float* p1w1 = (const float*)d_in[9];
    const float* p1w2 = (const float*)d_in[10];
    const float* p1b2 = (const float*)d_in[11];
    const float* b1   = (const float*)d_in[12];
    const float* W2   = (const float*)d_in[13];
    const float* h2w1 = (const float*)d_in[14];
    const float* h2w2 = (const float*)d_in[15];
    const float* h2b2 = (const float*)d_in[16];
    const float* p2w1 = (const float*)d_in[17];
    const float* p2w2 = (const float*)d_in[18];
    const float* p2b2 = (const float*)d_in[19];
    const float* b2   = (const float*)d_in[20];
    float* out = (float*)d_out;

    // ---- workspace bump allocator (~242 MB) ----
    char* p = (char*)d_ws;
    auto alloc = [&](size_t bytes) { char* r = p; p += (bytes + 255) & ~(size_t)255; return r; };

    char* r0    = alloc((size_t)64 * M_PAD * 16);          // 51.25 MB: xq (fp8 512B rows), then t1p
    u8*   xq    = (u8*)r0;
    u16*  t1p   = (u16*)r0;
    u16*  aggb  = (u16*)alloc((size_t)N_NODES * H1 * 2);   // 51.2 MB bf16
    char* ebr   = alloc((size_t)E_TOT * HID * 2);          // 83.2 MB: ebd (slot-ordered)
    u16*  ebd   = (u16*)ebr;
    u16*  ebd2  = (u16*)alloc((size_t)E_TOT * NCLS * 2);   // 20.8 MB
    char* xpr   = alloc((size_t)16 * M_PAD * 16);          // 12.81 MB: xp (frag-major x), then xh2p[4][M_PAD][16]
    u16*  xp    = (u16*)xpr;
    float* xh2p = (float*)xpr;
    float* sinv1= (float*)alloc((size_t)N_NODES * 64 * 4); // 12.8 MB layer-1 inv denominators
    u16*  W1p   = (u16*)alloc((size_t)16 * H1 * 16);       // 128 KB
    u16*  p1w2p = (u16*)alloc((size_t)64 * H1 * 16);       // 512 KB
    u16*  w1f   = (u16*)alloc(2048 * 2);                   // mlp1 w1 frags
    u16*  w2f   = (u16*)alloc(4096 * 2);                   // mlp1 w2 frags
    u16*  w3f   = (u16*)alloc(512 * 2);                    // mlp2 w1 frags
    u16*  w4f   = (u16*)alloc(512 * 2);                    // mlp2 w2 frags
    u16*  w2hf  = (u16*)alloc(8192 * 2);                   // W2 hi frags (16 ks x 64 lanes x 8)
    u16*  w2lf  = (u16*)alloc(8192 * 2);                   // W2 lo (residual) frags
    int* src_cnt  = (int*)alloc(N_NODES * 4);
    int* dst_cnt  = (int*)alloc(N_NODES * 4);
    int* src_cur  = (int*)alloc(N_NODES * 4);
    int* dst_cur  = (int*)alloc(N_NODES * 4);
    int* partials = (int*)alloc(2 * NBLK * 4);
    int* src_off  = (int*)alloc((N_NODES + 1) * 4);
    int* dst_off  = (int*)alloc((N_NODES + 1) * 4);
    int* src_list = (int*)alloc((size_t)E_TOT * 4);        // dst-slot ids grouped by src
    int* deid     = (int*)alloc((size_t)E_TOT * 4);        // dst slot -> edge id
    int* dsrc     = (int*)alloc((size_t)E_TOT * 4);        // dst slot -> src node
    float* z2   = (float*)alloc((size_t)N_NODES * NCLS * 4);   // inv2*xh2 fused table
    float* agg2 = (float*)alloc((size_t)N_NODES * NCLS * 4);
    float* inv2 = (float*)alloc((size_t)N_NODES * NCLS * 4);

    const dim3 blk(256);
    const int EB = (E_TOT + 255) / 256;
    const int WB = (N_NODES * 64 + 255) / 256;
    const int GB16 = (N_NODES + 15) / 16;
    const dim3 gmm(512 / 128, M_PAD / 128);                 // (4, 391)
    const int MLPB = (E_TOT / 16 + 3) / 4;

    // ---- CSR build + weight/layout conversion ----
    hipMemsetAsync(src_cnt, 0, (char*)partials - (char*)src_cnt, stream);
    count_k<<<EB, blk, 0, stream>>>(ei, src_cnt, dst_cnt);
    scanA_k<<<2 * NBLK, blk, 0, stream>>>(src_cnt, dst_cnt, partials);
    scanB_k<<<1, 512, 0, stream>>>(partials);
    scanC_k<<<2 * NBLK, blk, 0, stream>>>(src_cnt, dst_cnt, partials, src_off, dst_off);
    fillD_k<<<8 * FBPR, blk, 0, stream>>>(ei, dst_off, dst_cur, deid, dsrc);
    fillS_k<<<8 * FBPR, blk, 0, stream>>>(dsrc, src_off, src_cur, src_list);
    conv_a_k<<<(16 * M_PAD + 255) / 256, blk, 0, stream>>>(x, xp, N_NODES, M_PAD, F_IN);
    conv_b_k<<<(16 * H1 + 255) / 256, blk, 0, stream>>>(W1, W1p, F_IN, H1);
    conv_b_k<<<(64 * H1 + 255) / 256, blk, 0, stream>>>(p1w2, p1w2p, H1, H1);
    wfrag_all_k<<<92, blk, 0, stream>>>(h1w1, h1w2, h2w1, h2w2, W2,
                                        w1f, w2f, w3f, w4f, w2hf, w2lf);

    // ---- layer 1 (edge MLPs + denominators BEFORE the x@W1 GEMM so its epilogue can
    //      fuse the softmax scale + fp8 conversion; s2sum early too, feeding red4z) ----
    edge_mlps_k<<<MLPB, blk, 0, stream>>>(kr, deid, w1f, w2f, h1b2, w3f, w4f, h2b2, ebd, ebd2);
    s1sum_k<<<WB, blk, 0, stream>>>(ebd, src_off, src_list, sinv1);
    mfma_gemm_k<1><<<gmm, blk, 0, stream>>>(xp, W1p, (u16*)xq, N_NODES, M_PAD, H1, F_IN,
                                            nullptr, nullptr, nullptr, nullptr,
                                            nullptr, nullptr, nullptr, sinv1);
    msg1_k<<<WB, blk, 0, stream>>>(ebd, xq, dsrc, dst_off, aggb);
    gemm_t1_k<<<dim3(8, (N_NODES + 63) / 64), blk, 0, stream>>>(ep, p1w1, t1p);   // overwrites xq region
    // fused: h = relu(aggb + b1 + alpha*leaky(t1@p1w2 + p1b2)); xh2 partials = h @ W2 (MFMA)
    mfma_gemm_k<3><<<gmm, blk, 0, stream>>>(t1p, p1w2p, nullptr, N_NODES, M_PAD, H1, H1,
                                            p1b2, aggb, b1, alpha, w2hf, w2lf, xh2p, nullptr);

    // ---- layer 2: z2 = (sum partials)*inv2 -> single L2-resident gather table ----
    s2sum_k<<<GB16, blk, 0, stream>>>(ebd2, src_off, src_list, inv2);
    red4z_k<<<(N_NODES * 4 + 255) / 256, blk, 0, stream>>>(xh2p, inv2, z2);
    msg2_k<<<GB16, blk, 0, stream>>>(ebd2, z2, dsrc, dst_off, agg2);
    final_k<<<(N_NODES + 255) / 256, blk, 0, stream>>>(agg2, ep, p2w1, p2w2, p2b2, b2, alpha, out);
}

// Round 12
// 585.103 us; speedup vs baseline: 1.0606x; 1.0572x over previous
//
#include <hip/hip_runtime.h>
#include <math.h>

#define N_NODES 50000
#define M_PAD   50048    // N_NODES padded to multiple of 128 for MFMA tiles
#define N_EDGES 600000
#define E_TOT   650000   // N_EDGES + N_NODES (self loops appended)
#define F_IN    128
#define HID     64
#define HEADS   8
#define H1      512      // HEADS*HID
#define NCLS    16
#define NC      16
#define NCP     16
#define NBLK    ((N_NODES + 255) / 256)   // 196 scan blocks per array
#define FRNG    (N_NODES / 8)             // 6250 nodes per XCD range
#define FBPR    128                       // fill blocks per range
#define FPER    ((E_TOT + FBPR - 1) / FBPR)

typedef unsigned short u16;
typedef unsigned char  u8;
typedef __attribute__((ext_vector_type(8))) short short8;   // 8 bf16 = 4 VGPRs (MFMA A/B frag)
typedef __attribute__((ext_vector_type(4))) float f32x4;    // MFMA C/D frag
typedef __attribute__((ext_vector_type(2))) float f32x2;

__device__ __forceinline__ float bf2f(u16 h) {
    return __uint_as_float(((unsigned)h) << 16);
}
__device__ __forceinline__ u16 f2bf(float f) {
    unsigned u = __float_as_uint(f);
    u += 0x7fffu + ((u >> 16) & 1u);
    return (u16)(u >> 16);
}
__device__ __forceinline__ int edge_src(const int* __restrict__ ei, int e) {
    return (e < N_EDGES) ? ei[e] : (e - N_EDGES);
}
__device__ __forceinline__ int edge_dst(const int* __restrict__ ei, int e) {
    return (e < N_EDGES) ? ei[N_EDGES + e] : (e - N_EDGES);
}

// async global->LDS 16B copy: per-lane global src, wave-uniform LDS dest (+lane*16)
__device__ __forceinline__ void gload16(const void* g, void* l) {
    __builtin_amdgcn_global_load_lds(
        (const __attribute__((address_space(1))) unsigned int*)g,
        (__attribute__((address_space(3))) unsigned int*)l, 16, 0, 0);
}

// ---------------- CSR build ----------------
__global__ __launch_bounds__(256) void count_k(const int* __restrict__ ei,
                                               int* __restrict__ src_cnt, int* __restrict__ dst_cnt) {
    int e = blockIdx.x * 256 + threadIdx.x;
    if (e >= E_TOT) return;
    atomicAdd(&src_cnt[edge_src(ei, e)], 1);
    atomicAdd(&dst_cnt[edge_dst(ei, e)], 1);
}

// Phase A: per-block partial sums. grid = 2*NBLK (src blocks, then dst blocks).
__global__ __launch_bounds__(256) void scanA_k(const int* __restrict__ src_cnt,
                                               const int* __restrict__ dst_cnt,
                                               int* __restrict__ partials) {
    int pass = blockIdx.x >= NBLK;
    int b = blockIdx.x - pass * NBLK;
    const int* cnt = pass ? dst_cnt : src_cnt;
    int idx = b * 256 + threadIdx.x;
    int v = (idx < N_NODES) ? cnt[idx] : 0;
    __shared__ int red[4];
    #pragma unroll
    for (int off = 32; off; off >>= 1) v += __shfl_down(v, off, 64);
    if ((threadIdx.x & 63) == 0) red[threadIdx.x >> 6] = v;
    __syncthreads();
    if (threadIdx.x == 0) partials[blockIdx.x] = red[0] + red[1] + red[2] + red[3];
}

// Phase B: two independent exclusive scans of NBLK partials (src seg, dst seg), one block.
__global__ __launch_bounds__(512) void scanB_k(int* __restrict__ partials) {
    __shared__ int lds[512];
    int t = threadIdx.x;           // 512 threads: t<256 -> src segment, else dst
    int seg = t >> 8, i = t & 255;
    int v = (i < NBLK) ? partials[seg * NBLK + i] : 0;
    lds[t] = v;
    __syncthreads();
    for (int d = 1; d < 256; d <<= 1) {
        int x = (i >= d) ? lds[seg * 256 + i - d] : 0;
        __syncthreads();
        lds[t] += x;
        __syncthreads();
    }
    if (i < NBLK) partials[seg * NBLK + i] = lds[t] - v;   // exclusive
}

// Phase C: block-local exclusive scan + block offset -> off[]; off[N]=E_TOT constant.
__global__ __launch_bounds__(256) void scanC_k(const int* __restrict__ src_cnt,
                                               const int* __restrict__ dst_cnt,
                                               const int* __restrict__ partials,
                                               int* __restrict__ src_off, int* __restrict__ dst_off) {
    int pass = blockIdx.x >= NBLK;
    int b = blockIdx.x - pass * NBLK;
    const int* cnt = pass ? dst_cnt : src_cnt;
    int* off = pass ? dst_off : src_off;
    int base = partials[blockIdx.x];
    __shared__ int lds[256];
    int t = threadIdx.x;
    int idx = b * 256 + t;
    int v = (idx < N_NODES) ? cnt[idx] : 0;
    lds[t] = v;
    __syncthreads();
    for (int d = 1; d < 256; d <<= 1) {
        int x = (t >= d) ? lds[t - d] : 0;
        __syncthreads();
        lds[t] += x;
        __syncthreads();
    }
    if (idx < N_NODES) off[idx] = base + lds[t] - v;
    if (b == 0 && t == 0) off[N_NODES] = E_TOT;
}

// ---- fill pass D (XCD-range partitioned by dst): dsrc[slot]=src, deid[slot]=edge id.
__global__ __launch_bounds__(256) void fillD_k(const int* __restrict__ ei,
                                               const int* __restrict__ dst_off, int* __restrict__ dst_cur,
                                               int* __restrict__ deid, int* __restrict__ dsrc) {
    const int range = blockIdx.x & 7, slice = blockIdx.x >> 3;
    const int d0 = range * FRNG, d1 = d0 + FRNG;
    const int e0 = slice * FPER;
    const int e1 = (e0 + FPER < E_TOT) ? e0 + FPER : E_TOT;
    for (int e = e0 + threadIdx.x; e < e1; e += 256) {
        int d = edge_dst(ei, e);
        if (d < d0 || d >= d1) continue;
        int rd = dst_off[d] + atomicAdd(&dst_cur[d], 1);
        deid[rd] = e;
        dsrc[rd] = edge_src(ei, e);
    }
}

// ---- fill pass S (XCD-range partitioned by src): src_list[src slot] = dst-slot id.
__global__ __launch_bounds__(256) void fillS_k(const int* __restrict__ dsrc,
                                               const int* __restrict__ src_off, int* __restrict__ src_cur,
                                               int* __restrict__ src_list) {
    const int range = blockIdx.x & 7, slice = blockIdx.x >> 3;
    const int s0 = range * FRNG, s1 = s0 + FRNG;
    const int r0 = slice * FPER;
    const int r1 = (r0 + FPER < E_TOT) ? r0 + FPER : E_TOT;
    for (int rd = r0 + threadIdx.x; rd < r1; rd += 256) {
        int s = dsrc[rd];
        if (s < s0 || s >= s1) continue;
        src_list[src_off[s] + atomicAdd(&src_cur[s], 1)] = rd;
    }
}

// ---------------- layout converters ----------------
// f32 [M][K] row-major -> bf16 fragment-major Ap[K/8][Mp][8]; pad rows zeroed
__global__ __launch_bounds__(256) void conv_a_k(const float* __restrict__ A, u16* __restrict__ Ap,
                                                int M, int Mp, int K) {
    int i = blockIdx.x * 256 + threadIdx.x;
    int total = (K >> 3) * Mp;
    if (i >= total) return;
    int r = i % Mp;
    int kb = i / Mp;
    u16* o = Ap + (size_t)i * 8;
    u16 tmp[8];
    if (r < M) {
        const float* a = A + (size_t)r * K + kb * 8;
        #pragma unroll
        for (int j = 0; j < 8; ++j) tmp[j] = f2bf(a[j]);
    } else {
        #pragma unroll
        for (int j = 0; j < 8; ++j) tmp[j] = 0;
    }
    *(ushort4*)o = *(ushort4*)tmp;
    *(ushort4*)(o + 4) = *(ushort4*)(tmp + 4);
}

// f32 [K][N] row-major -> bf16 fragment-major Bp[K/8][N][8] (Bp[kb][n][j] = B[kb*8+j][n])
__global__ __launch_bounds__(256) void conv_b_k(const float* __restrict__ B, u16* __restrict__ Bp,
                                                int K, int N) {
    int i = blockIdx.x * 256 + threadIdx.x;
    int total = (K >> 3) * N;
    if (i >= total) return;
    int n = i % N;
    int kb = i / N;
    u16 tmp[8];
    #pragma unroll
    for (int j = 0; j < 8; ++j) tmp[j] = f2bf(B[(size_t)(kb * 8 + j) * N + n]);
    u16* o = Bp + (size_t)i * 8;
    *(ushort4*)o = *(ushort4*)tmp;
    *(ushort4*)(o + 4) = *(ushort4*)(tmp + 4);
}

// per-lane B-frag layout tables for MFMA 16x16x32
__device__ __forceinline__ void wfrag_one(const float* W, u16* o, int i, int K, int N) {
    int j = i & 7, lane = (i >> 3) & 63, rest = i >> 9;
    int nt = rest % (N / 16), ks = rest / (N / 16);
    int lm = lane & 15, quad = lane >> 4;
    int k = ks * 32 + quad * 8 + j, n = nt * 16 + lm;
    o[i] = (k < K) ? f2bf(W[(size_t)k * N + n]) : (u16)0;
}
// residual table: lo = bf16(W - bf16(W)) so hi+lo MFMA pair == f32-precision W
__device__ __forceinline__ void wfrag_res(const float* W, u16* o, int i, int K, int N) {
    int j = i & 7, lane = (i >> 3) & 63, rest = i >> 9;
    int nt = rest % (N / 16), ks = rest / (N / 16);
    int lm = lane & 15, quad = lane >> 4;
    int k = ks * 32 + quad * 8 + j, n = nt * 16 + lm;
    float w = (k < K) ? W[(size_t)k * N + n] : 0.f;
    o[i] = f2bf(w - bf2f(f2bf(w)));
}
__global__ __launch_bounds__(256) void wfrag_all_k(
    const float* __restrict__ h1w1, const float* __restrict__ h1w2,
    const float* __restrict__ h2w1, const float* __restrict__ h2w2,
    const float* __restrict__ W2,
    u16* __restrict__ w1f, u16* __restrict__ w2f,
    u16* __restrict__ w3f, u16* __restrict__ w4f,
    u16* __restrict__ w2hf, u16* __restrict__ w2lf) {
    int i = blockIdx.x * 256 + threadIdx.x;   // total 7168 + 2*8192 = 23552
    if (i < 2048)       wfrag_one(h1w1, w1f, i, 16, 64);          // Kpad 32, N 64
    else if (i < 6144)  wfrag_one(h1w2, w2f, i - 2048, 64, 64);   // Kpad 64, N 64
    else if (i < 6656)  wfrag_one(h2w1, w3f, i - 6144, 16, 16);
    else if (i < 7168)  wfrag_one(h2w2, w4f, i - 6656, 16, 16);
    else if (i < 15360) wfrag_one(W2, w2hf, i - 7168, 512, 16);   // W2 hi frags (16 ks chunks)
    else if (i < 23552) wfrag_res(W2, w2lf, i - 15360, 512, 16);  // W2 lo (residual) frags
}

// ---------------- MFMA GEMM: frag-major operands, 128x128 tile, 4 waves ----------------
// K-loop (round-9 proven): A triple-buffered in LDS (3x8KB) with counted-vmcnt depth-2
// prefetch; B (L2-hot) in REGISTERS with depth-1 ping-pong; B(ts) issued before A(ts+1)
// so B-waits never retire the A prefetch. LDS 32KB (epilogue Tf aliases the A buffers;
// Hs aliases Tf's first half) and __launch_bounds__(256,4) -> 4 blocks/CU.
// EPI==1 (x @ W1 path): h1 = acc is NOT stored as bf16; the epilogue applies the
//   ex-s1inv phase-2 chain directly: y = bf2f(f2bf(acc)) * sinv[row][ch&63] -> fp8
//   and writes the 512B-stride fp8 gather table. Requires sinv precomputed (ssum_k).
// EPI==3 (t1 @ p1w2 path): h = relu(extra + bias2 + alpha*leaky(acc + bias, 0.01)) is
//   NOT stored; bf16(h) goes through the XOR-swizzled Hs tile and the MATRIX pipe:
//   xh2 partial = h @ (W2hi+W2lo), W2 frags loaded per-kc from L2-hot tables.
template<int EPI>
__global__ __launch_bounds__(256, 4) void mfma_gemm_k(
    const u16* __restrict__ Ap, const u16* __restrict__ Bp, u16* __restrict__ C,
    int M, int Mp, int Nn, int K,
    const float* __restrict__ bias, const u16* __restrict__ extra,
    const float* __restrict__ bias2, const float* __restrict__ alpha_p,
    const u16* __restrict__ w2hf, const u16* __restrict__ w2lf,
    float* __restrict__ xh2p, const float* __restrict__ sinvp)
{
    __shared__ __align__(16) char LSD[32768];   // loop: 3x8KB A bufs; epilogue: Tf 32KB
    const int t = threadIdx.x;
    const int wave = t >> 6, lane = t & 63;
    const int wm = (wave >> 1) * 64, wn = (wave & 1) * 64;
    const int lm = lane & 15, quad = lane >> 4;

    // bijective XCD-chunk swizzle (m204 formula); dispatch->XCD assumed bid%8.
    const int nwg = (int)(gridDim.y << 2);
    const int bid = (int)(blockIdx.y * 4 + blockIdx.x);
    const int qq = nwg >> 3, rr8 = nwg & 7;
    const int xcd = bid & 7, idx = bid >> 3;
    const int wg = (xcd < rr8 ? xcd * (qq + 1) : rr8 * (qq + 1) + (xcd - rr8) * qq) + idx;
    const int bn = (wg & 3) * 128;
    const int bm = (wg >> 2) * 128;

    const char* Ab = (const char*)Ap;
    size_t cbase[4];
    #pragma unroll
    for (int nj = 0; nj < 4; ++nj) cbase[nj] = (size_t)(bn + wn + nj * 16 + lm) * 8;

    f32x4 acc[4][4] = {};
    const int NT = K >> 5;   // K-steps of 32 (4 or 16, even)

    // stage K-step ts's A tile (8 KB) into buffer b: 2 gload16 per wave
    auto stageA = [&](int b, int ts) {
        const int kb0 = ts * 4;
        #pragma unroll
        for (int h = 0; h < 2; ++h) {
            const int ob = h * 4096 + wave * 1024;     // wave-uniform LDS byte base
            const int kb = kb0 + (ob >> 11);           // which k/8 chunk
            const int rem = (ob & 1024) + lane * 16;   // byte offset inside 2 KB chunk
            gload16(Ab + ((size_t)kb * Mp + bm) * 16 + rem, LSD + b * 8192 + ob);
        }
    };
    // B fragments for K-step ts: 4 x 16B per lane, straight from L2
    auto loadB = [&](short8 (&bf)[4], int ts) {
        const u16* Bq = Bp + (size_t)(ts * 4 + quad) * Nn * 8;
        #pragma unroll
        for (int nj = 0; nj < 4; ++nj) bf[nj] = *(const short8*)(Bq + cbase[nj]);
    };
    auto compute = [&](int cb, short8 (&bf)[4]) {
        const u16* As = (const u16*)(LSD + cb * 8192);
        short8 af[4];
        #pragma unroll
        for (int mi = 0; mi < 4; ++mi)
            af[mi] = *(const short8*)(As + quad * 1024 + (wm + mi * 16 + lm) * 8);
        #pragma unroll
        for (int mi = 0; mi < 4; ++mi)
            #pragma unroll
            for (int nj = 0; nj < 4; ++nj)
                acc[mi][nj] = __builtin_amdgcn_mfma_f32_16x16x32_bf16(af[mi], bf[nj], acc[mi][nj], 0, 0, 0);
    };

    short8 b0[4], b1[4];
    stageA(0, 0);        // A0 (oldest)
    loadB(b0, 0);        // B0 before A1: B-waits never retire the A prefetch
    stageA(1, 1);        // A1
    #pragma unroll 1
    for (int ts = 0; ts < NT - 2; ts += 2) {
        asm volatile("s_waitcnt vmcnt(6)" ::: "memory");   // A(ts) landed (mine)
        __builtin_amdgcn_sched_barrier(0);
        __builtin_amdgcn_s_barrier();                      // => everyone's A(ts) landed
        loadB(b1, ts + 1);
        stageA((ts + 2) % 3, ts + 2);
        compute(ts % 3, b0);
        asm volatile("s_waitcnt vmcnt(6)" ::: "memory");   // A(ts+1) landed
        __builtin_amdgcn_sched_barrier(0);
        __builtin_amdgcn_s_barrier();
        loadB(b0, ts + 2);
        stageA((ts + 3) % 3, ts + 3);
        compute((ts + 1) % 3, b1);
    }
    // ts = NT-2
    asm volatile("s_waitcnt vmcnt(6)" ::: "memory");
    __builtin_amdgcn_sched_barrier(0);
    __builtin_amdgcn_s_barrier();
    loadB(b1, NT - 1);
    compute((NT - 2) % 3, b0);
    // ts = NT-1
    asm volatile("s_waitcnt vmcnt(4)" ::: "memory");       // A(NT-1) landed
    __builtin_amdgcn_sched_barrier(0);
    __builtin_amdgcn_s_barrier();
    compute((NT - 1) % 3, b1);
    __syncthreads();            // full rendezvous before epilogue reuses LSD

    // ---- epilogue: acc -> 64x128 f32 LDS tile Tf (XOR swizzle) -> consume ----
    float* Tf = (float*)LSD;
    const float alpha = (EPI == 3) ? *alpha_p : 0.f;
    #pragma unroll
    for (int pass = 0; pass < 2; ++pass) {
        if ((wave >> 1) == pass) {
            #pragma unroll
            for (int mi = 0; mi < 4; ++mi)
                #pragma unroll
                for (int r4 = 0; r4 < 4; ++r4) {
                    const int lr = mi * 16 + quad * 4 + r4;
                    const int sw = (lr & 7) << 2;
                    #pragma unroll
                    for (int nj = 0; nj < 4; ++nj)
                        Tf[lr * 128 + ((wn + nj * 16 + lm) ^ sw)] = acc[mi][nj][r4];
                }
        }
        __syncthreads();
        if (EPI == 1) {
            // fused ex-s1inv phase 2: y = bf16round(acc) * sinv -> fp8 table (512B rows)
            const int lrow = t & 63, chunk = t >> 6;
            const int col0 = chunk * 32;
            const int rr = bm + pass * 64 + lrow;
            if (rr < M) {
                const int sw = (lrow & 7) << 2;
                float v[32];
                #pragma unroll
                for (int j4 = 0; j4 < 8; ++j4) {
                    float4 f = *(const float4*)&Tf[lrow * 128 + ((col0 + j4 * 4) ^ sw)];
                    v[j4 * 4] = f.x; v[j4 * 4 + 1] = f.y; v[j4 * 4 + 2] = f.z; v[j4 * 4 + 3] = f.w;
                }
                const int gc0 = bn + col0;
                const float* sv = sinvp + (size_t)rr * 64 + (gc0 & 63);  // 32 consecutive
                int pw[8];
                #pragma unroll
                for (int g = 0; g < 8; ++g) {
                    float y0 = bf2f(f2bf(v[g * 4 + 0])) * sv[g * 4 + 0];
                    float y1 = bf2f(f2bf(v[g * 4 + 1])) * sv[g * 4 + 1];
                    float y2 = bf2f(f2bf(v[g * 4 + 2])) * sv[g * 4 + 2];
                    float y3 = bf2f(f2bf(v[g * 4 + 3])) * sv[g * 4 + 3];
                    int p0 = __builtin_amdgcn_cvt_pk_fp8_f32(y0, y1, 0, false);
                    pw[g] = __builtin_amdgcn_cvt_pk_fp8_f32(y2, y3, p0, true);
                }
                u8* dst = (u8*)C + (size_t)rr * 512 + gc0;
                *(uint4*)dst        = make_uint4(pw[0], pw[1], pw[2], pw[3]);
                *(uint4*)(dst + 16) = make_uint4(pw[4], pw[5], pw[6], pw[7]);
            }
        } else {
            u8* HsB = (u8*)LSD;                  // aliases Tf's first 16KB (barrier-guarded)
            const int row = wave * 16 + lm;      // 0..63 (one h-row per lane)
            const int col0 = quad * 32;
            const int rr = bm + pass * 64 + row;
            const int gc0 = bn + col0;
            u16 hpk[32];
            if (rr < M) {
                const int sw = (row & 7) << 2;
                const u16* ex = extra + (size_t)rr * Nn + gc0;
                #pragma unroll
                for (int g = 0; g < 4; ++g) {
                    float4 f0 = *(const float4*)&Tf[row * 128 + ((col0 + g * 8) ^ sw)];
                    float4 f1 = *(const float4*)&Tf[row * 128 + ((col0 + g * 8 + 4) ^ sw)];
                    float vv8[8] = {f0.x, f0.y, f0.z, f0.w, f1.x, f1.y, f1.z, f1.w};
                    short8 e8 = *(const short8*)(ex + g * 8);
                    #pragma unroll
                    for (int j = 0; j < 8; ++j) {
                        const int cj = g * 8 + j;
                        float vv = vv8[j] + bias[gc0 + cj];
                        vv = vv > 0.f ? vv : 0.01f * vv;
                        float o = bf2f((u16)e8[j]) + bias2[gc0 + cj] + alpha * vv;
                        o = fmaxf(o, 0.f);
                        hpk[cj] = f2bf(o);      // identical to the old hb bf16 value
                    }
                }
            } else {
                #pragma unroll
                for (int j = 0; j < 32; ++j) hpk[j] = 0;
            }
            __syncthreads();                     // all Tf reads done before Hs overwrite
            // bf16 h row -> Hs (XOR-swizzled 16B slots: bank-clean write AND read)
            #pragma unroll
            for (int g = 0; g < 4; ++g) {
                const int ba = (row * 256 + quad * 64 + g * 16) ^ ((row & 7) << 4);
                *(short8*)(HsB + ba) = *(const short8*)&hpk[g * 8];
            }
            __syncthreads();
            // A-frags from Hs; xh2 partial = h @ (W2hi + W2lo) on the matrix pipe.
            // W2 hi/lo frags loaded per-kc from L2-hot tables (transient regs).
            f32x4 axh = {};
            const int ksb = bn >> 5;
            #pragma unroll
            for (int kc = 0; kc < 4; ++kc) {
                const int ba = (row * 256 + kc * 64 + quad * 16) ^ ((row & 7) << 4);
                short8 ha = *(const short8*)(HsB + ba);
                short8 wh = *(const short8*)(w2hf + ((size_t)(ksb + kc) * 64 + lane) * 8);
                short8 wl = *(const short8*)(w2lf + ((size_t)(ksb + kc) * 64 + lane) * 8);
                axh = __builtin_amdgcn_mfma_f32_16x16x32_bf16(ha, wh, axh, 0, 0, 0);
                axh = __builtin_amdgcn_mfma_f32_16x16x32_bf16(ha, wl, axh, 0, 0, 0);
            }
            // C/D layout: col = lane&15, row = quad*4 + reg
            #pragma unroll
            for (int r = 0; r < 4; ++r) {
                const int prow = bm + pass * 64 + wave * 16 + quad * 4 + r;
                if (prow < M)
                    xh2p[((size_t)(bn >> 7) * M_PAD + prow) * 16 + lm] = axh[r];
            }
        }
        __syncthreads();
    }
}

// ---------------- z2 = (sum of 4 xh2 partials) * inv2  (layer-2 fused gather table) ----------------
__global__ __launch_bounds__(256) void red4z_k(const float* __restrict__ xh2p,
                                               const float* __restrict__ inv2,
                                               float* __restrict__ z2) {
    int i = blockIdx.x * 256 + threadIdx.x;     // float4 index over [N_NODES][16]
    if (i >= N_NODES * 4) return;
    const float4* P = (const float4*)xh2p;
    const size_t S = (size_t)M_PAD * 4;         // float4s per slice
    float4 a = P[i], b = P[S + i], c = P[2 * S + i], d = P[3 * S + i];
    float4 iv = ((const float4*)inv2)[i];
    float4 r;
    r.x = ((a.x + b.x) + (c.x + d.x)) * iv.x;
    r.y = ((a.y + b.y) + (c.y + d.y)) * iv.y;
    r.z = ((a.z + b.z) + (c.z + d.z)) * iv.z;
    r.w = ((a.w + b.w) + (c.w + d.w)) * iv.w;
    ((float4*)z2)[i] = r;
}

// ---------------- t1 = leaky(ep @ p1w1, 0.2), K=16, written in frag-major Ap layout ----------------
__global__ __launch_bounds__(256) void gemm_t1_k(
    const float* __restrict__ ep, const float* __restrict__ W, u16* __restrict__ t1p)
{
    __shared__ float Bs[16][64];
    const int bm = blockIdx.y * 64, bn = blockIdx.x * 64;
    const int t = threadIdx.x;
    const int tx = t & 15, ty = t >> 4;
    *(float4*)&Bs[t >> 4][(t & 15) * 4] = *(const float4*)&W[(size_t)(t >> 4) * H1 + bn + (t & 15) * 4];
    __syncthreads();
    const int r0 = bm + ty * 4;
    const int c0 = bn + tx * 4;
    for (int i = 0; i < 4; ++i) {
        int r = r0 + i;
        if (r >= N_NODES) continue;
        float av[16];
        #pragma unroll
        for (int j4 = 0; j4 < 16; j4 += 4) {
            float4 v = *(const float4*)(ep + (size_t)r * NCP + j4);
            av[j4] = v.x; av[j4 + 1] = v.y; av[j4 + 2] = v.z; av[j4 + 3] = v.w;
        }
        u16 pk[4];
        #pragma unroll
        for (int q = 0; q < 4; ++q) {
            float s = 0.f;
            #pragma unroll
            for (int k = 0; k < 16; ++k) s = fmaf(av[k], Bs[k][tx * 4 + q], s);
            s = s > 0.f ? s : 0.2f * s;
            pk[q] = f2bf(s);
        }
        u16* o = t1p + ((size_t)(c0 >> 3) * M_PAD + r) * 8 + (c0 & 7);
        *(ushort4*)o = *(ushort4*)pk;
    }
}

// ---------------- fused MFMA edge MLPs, SLOT-ordered: gather kr via deid, ----------------
// ---------------- write ebd / ebd2 fully sequentially (no scatter)        ----------------
#define TSTR 72   // LDS tile row stride in bf16 elems (144 B: 16B-aligned frag reads, <=2-way banks)
__global__ __launch_bounds__(256) void edge_mlps_k(
    const float* __restrict__ kr, const int* __restrict__ deid,
    const u16* __restrict__ w1f, const u16* __restrict__ w2f, const float* __restrict__ b2a,
    const u16* __restrict__ w3f, const u16* __restrict__ w4f, const float* __restrict__ b2b,
    u16* __restrict__ ebd, u16* __restrict__ ebd2)
{
    __shared__ __align__(16) u16 T[4][16 * TSTR];
    const int t = threadIdx.x, wv = t >> 6, lane = t & 63;
    const int lm = lane & 15, quad = lane >> 4;
    const int tile = blockIdx.x * 4 + wv;
    const int s0 = tile * 16;          // dst-slot base (16 consecutive slots)
    if (s0 >= E_TOT) return;
    u16* Tw = T[wv];

    // weight fragments -> VGPRs (per-lane)
    short8 W1[4], W2[2][4];
    #pragma unroll
    for (int nt = 0; nt < 4; ++nt) W1[nt] = *(const short8*)(w1f + ((size_t)nt * 64 + lane) * 8);
    #pragma unroll
    for (int ks = 0; ks < 2; ++ks)
        #pragma unroll
        for (int nt = 0; nt < 4; ++nt)
            W2[ks][nt] = *(const short8*)(w2f + (((size_t)ks * 4 + nt) * 64 + lane) * 8);
    short8 W3 = *(const short8*)(w3f + (size_t)lane * 8);
    short8 W4 = *(const short8*)(w4f + (size_t)lane * 8);
    float b2av[4];
    #pragma unroll
    for (int nt = 0; nt < 4; ++nt) b2av[nt] = b2a[nt * 16 + lm];
    float b2bv = b2b[lm];

    // A-frag: slot row m = s0+lm -> edge e = deid[s0+lm]; k = quad*8+j (K=16 padded to 32)
    const int e = deid[s0 + lm];
    short8 af = {};
    if (quad < 2) {
        const float* kp = kr + (size_t)e * NC + quad * 8;
        float4 v0 = *(const float4*)kp;
        float4 v1 = *(const float4*)(kp + 4);
        u16 tmp[8] = {f2bf(v0.x), f2bf(v0.y), f2bf(v0.z), f2bf(v0.w),
                      f2bf(v1.x), f2bf(v1.y), f2bf(v1.z), f2bf(v1.w)};
        af = *(const short8*)tmp;
    }

    // ---- MLP1 layer 1: [16 slots x 64] = kr @ w1, leaky 0.2 ----
    f32x4 a1[4] = {};
    #pragma unroll
    for (int nt = 0; nt < 4; ++nt)
        a1[nt] = __builtin_amdgcn_mfma_f32_16x16x32_bf16(af, W1[nt], a1[nt], 0, 0, 0);
    #pragma unroll
    for (int nt = 0; nt < 4; ++nt)
        #pragma unroll
        for (int r = 0; r < 4; ++r) {
            float v = a1[nt][r];
            v = v > 0.f ? v : 0.2f * v;
            Tw[(quad * 4 + r) * TSTR + nt * 16 + lm] = f2bf(v);
        }
    __builtin_amdgcn_s_waitcnt(0);   // drain LDS writes before same-wave reads

    // ---- MLP1 layer 2: K=64 from LDS tile ----
    short8 a2[2];
    #pragma unroll
    for (int ks = 0; ks < 2; ++ks)
        a2[ks] = *(const short8*)&Tw[lm * TSTR + ks * 32 + quad * 8];
    f32x4 c2[4] = {};
    #pragma unroll
    for (int nt = 0; nt < 4; ++nt)
        #pragma unroll
        for (int ks = 0; ks < 2; ++ks)
            c2[nt] = __builtin_amdgcn_mfma_f32_16x16x32_bf16(a2[ks], W2[ks][nt], c2[nt], 0, 0, 0);
    // epilogue: + b2, exp -> LDS
    #pragma unroll
    for (int nt = 0; nt < 4; ++nt)
        #pragma unroll
        for (int r = 0; r < 4; ++r)
            Tw[(quad * 4 + r) * TSTR + nt * 16 + lm] = f2bf(__expf(c2[nt][r] + b2av[nt]));
    __builtin_amdgcn_s_waitcnt(0);
    // repack: rows are consecutive slots -> 2 KB fully-contiguous store per wave
    #pragma unroll
    for (int p = 0; p < 2; ++p) {
        int c = p * 64 + lane;
        int row = c >> 3, off = (c & 7) * 8;
        short8 v = *(const short8*)&Tw[row * TSTR + off];
        *(short8*)(ebd + (size_t)(s0 + row) * HID + off) = v;
    }

    // ---- MLP2 (16->16->16), reuses kr A-frag ----
    f32x4 b1 = __builtin_amdgcn_mfma_f32_16x16x32_bf16(af, W3, (f32x4){}, 0, 0, 0);
    __builtin_amdgcn_s_waitcnt(0);   // eb repack reads done before overwrite
    #pragma unroll
    for (int r = 0; r < 4; ++r) {
        float v = b1[r];
        v = v > 0.f ? v : 0.2f * v;
        Tw[(quad * 4 + r) * TSTR + lm] = f2bf(v);
    }
    __builtin_amdgcn_s_waitcnt(0);
    // A-frag: cols 16..31 hold stale finite values, but W4 is zero there -> no effect
    short8 a3 = *(const short8*)&Tw[lm * TSTR + quad * 8];
    f32x4 c3 = __builtin_amdgcn_mfma_f32_16x16x32_bf16(a3, W4, (f32x4){}, 0, 0, 0);
    #pragma unroll
    for (int r = 0; r < 4; ++r)
        Tw[(quad * 4 + r) * TSTR + lm] = f2bf(__expf(c3[r] + b2bv));
    __builtin_amdgcn_s_waitcnt(0);
    if (lane < 32) {
        int row = lane >> 1, off = (lane & 1) * 8;
        short8 v = *(const short8*)&Tw[row * TSTR + off];
        *(short8*)(ebd2 + (size_t)(s0 + row) * NCLS + off) = v;   // 512 B contiguous per wave
    }
}

// ---------------- MERGED src-CSR denominators (wave per src, ONE src_list pass): ----------------
// sinv[N][64] = 1/(sum ebd rows), inv2[N][16] = 1/(sum ebd2 rows). The ebd2 gather rides
// the same index stream as the ebd gather (32B row alongside the 128B row per slot).
__global__ __launch_bounds__(256) void ssum_k(
    const u16* __restrict__ ebd, const u16* __restrict__ ebd2,
    const int* __restrict__ src_off, const int* __restrict__ src_list,
    float* __restrict__ sinv, float* __restrict__ inv2)
{
    int gid = blockIdx.x * 256 + threadIdx.x;
    int wid = gid >> 6, lane = gid & 63;
    if (wid >= N_NODES) return;
    const int c2 = lane & 15;      // ebd2 channel (4 lanes per channel, line-shared)
    int o0 = src_off[wid], o1 = src_off[wid + 1];
    float s0 = 0.f, s1 = 0.f, s2 = 0.f, s3 = 0.f;
    float t0 = 0.f, t1 = 0.f, t2 = 0.f, t3 = 0.f;
    int i = o0;
    for (; i + 3 < o1; i += 4) {
        int l0 = src_list[i], l1 = src_list[i + 1], l2 = src_list[i + 2], l3 = src_list[i + 3];
        s0 += bf2f(ebd[(size_t)l0 * HID + lane]);
        s1 += bf2f(ebd[(size_t)l1 * HID + lane]);
        s2 += bf2f(ebd[(size_t)l2 * HID + lane]);
        s3 += bf2f(ebd[(size_t)l3 * HID + lane]);
        t0 += bf2f(ebd2[(size_t)l0 * NCLS + c2]);
        t1 += bf2f(ebd2[(size_t)l1 * NCLS + c2]);
        t2 += bf2f(ebd2[(size_t)l2 * NCLS + c2]);
        t3 += bf2f(ebd2[(size_t)l3 * NCLS + c2]);
    }
    for (; i < o1; ++i) {
        int sl = src_list[i];
        s0 += bf2f(ebd[(size_t)sl * HID + lane]);
        t0 += bf2f(ebd2[(size_t)sl * NCLS + c2]);
    }
    sinv[(size_t)wid * 64 + lane] = 1.f / (((s0 + s1) + (s2 + s3)) + 1e-16f);
    if (lane < 16)
        inv2[(size_t)wid * NCLS + lane] = 1.f / (((t0 + t1) + (t2 + t3)) + 1e-16f);
}

// ---------------- message pass 1: wave per dst, sequential slots, fp8 gather, unroll 4 ----------------
__global__ __launch_bounds__(256) void msg1_k(
    const u16* __restrict__ ebd, const u8* __restrict__ xq,
    const int* __restrict__ dsrc, const int* __restrict__ dst_off,
    u16* __restrict__ aggb)
{
    int gid = blockIdx.x * 256 + threadIdx.x;
    int wid = gid >> 6, lane = gid & 63;
    if (wid >= N_NODES) return;
    int o0 = dst_off[wid], o1 = dst_off[wid + 1];
    const int a_off = (lane & 7) * 8;     // alpha channel block (ch = lane*8+j mod 64)
    float acc[8] = {};
    int i = o0;
    for (; i + 3 < o1; i += 4) {
        int s0 = __builtin_nontemporal_load(dsrc + i);
        int s1 = __builtin_nontemporal_load(dsrc + i + 1);
        int s2 = __builtin_nontemporal_load(dsrc + i + 2);
        int s3 = __builtin_nontemporal_load(dsrc + i + 3);
        short8 a0 = __builtin_nontemporal_load((const short8*)(ebd + (size_t)i * HID + a_off));
        short8 a1 = __builtin_nontemporal_load((const short8*)(ebd + (size_t)(i + 1) * HID + a_off));
        short8 a2 = __builtin_nontemporal_load((const short8*)(ebd + (size_t)(i + 2) * HID + a_off));
        short8 a3 = __builtin_nontemporal_load((const short8*)(ebd + (size_t)(i + 3) * HID + a_off));
        uint2 q0 = *(const uint2*)(xq + (size_t)s0 * 512 + lane * 8);
        uint2 q1 = *(const uint2*)(xq + (size_t)s1 * 512 + lane * 8);
        uint2 q2 = *(const uint2*)(xq + (size_t)s2 * 512 + lane * 8);
        uint2 q3 = *(const uint2*)(xq + (size_t)s3 * 512 + lane * 8);
        const uint2 qs[4] = {q0, q1, q2, q3};
        const short8 as[4] = {a0, a1, a2, a3};
        #pragma unroll
        for (int u = 0; u < 4; ++u) {
            f32x2 d0 = __builtin_amdgcn_cvt_pk_f32_fp8((int)qs[u].x, false);
            f32x2 d1 = __builtin_amdgcn_cvt_pk_f32_fp8((int)qs[u].x, true);
            f32x2 d2 = __builtin_amdgcn_cvt_pk_f32_fp8((int)qs[u].y, false);
            f32x2 d3 = __builtin_amdgcn_cvt_pk_f32_fp8((int)qs[u].y, true);
            float xv[8] = {d0.x, d0.y, d1.x, d1.y, d2.x, d2.y, d3.x, d3.y};
            #pragma unroll
            for (int j = 0; j < 8; ++j)
                acc[j] = fmaf(bf2f((u16)as[u][j]), xv[j], acc[j]);
        }
    }
    for (; i < o1; ++i) {
        int s = __builtin_nontemporal_load(dsrc + i);
        short8 a8 = __builtin_nontemporal_load((const short8*)(ebd + (size_t)i * HID + a_off));
        uint2 q = *(const uint2*)(xq + (size_t)s * 512 + lane * 8);
        f32x2 d0 = __builtin_amdgcn_cvt_pk_f32_fp8((int)q.x, false);
        f32x2 d1 = __builtin_amdgcn_cvt_pk_f32_fp8((int)q.x, true);
        f32x2 d2 = __builtin_amdgcn_cvt_pk_f32_fp8((int)q.y, false);
        f32x2 d3 = __builtin_amdgcn_cvt_pk_f32_fp8((int)q.y, true);
        float xv[8] = {d0.x, d0.y, d1.x, d1.y, d2.x, d2.y, d3.x, d3.y};
        #pragma unroll
        for (int j = 0; j < 8; ++j)
            acc[j] = fmaf(bf2f((u16)a8[j]), xv[j], acc[j]);
    }
    u16 pk[8];
    #pragma unroll
    for (int j = 0; j < 8; ++j) pk[j] = f2bf(acc[j]);
    __builtin_nontemporal_store(*(const short8*)pk, (short8*)(aggb + (size_t)wid * H1 + lane * 8));
}

// ---------------- message pass 2 (16 threads per dst): acc += ebd2[i] * z2[src] ----------------
// z2 = inv2*xh2 precomputed per node (3.2 MB, ~L2-resident) -> ONE random gather per edge
__global__ __launch_bounds__(256) void msg2_k(
    const u16* __restrict__ ebd2, const float* __restrict__ z2,
    const int* __restrict__ dsrc, const int* __restrict__ dst_off,
    float* __restrict__ agg2)
{
    int t = threadIdx.x;
    int g = blockIdx.x * 16 + (t >> 4), c = t & 15;
    if (g >= N_NODES) return;
    int o0 = dst_off[g], o1 = dst_off[g + 1];
    float acc = 0.f;
    for (int i = o0; i < o1; ++i) {
        int s = dsrc[i];
        float a = bf2f(ebd2[(size_t)i * NCLS + c]);
        acc = fmaf(a, z2[(size_t)s * NCLS + c], acc);
    }
    agg2[(size_t)g * NCLS + c] = acc;
}

// ---------------- final: o = agg2 + bias2 + alpha*p2; log_softmax ----------------
__global__ __launch_bounds__(256) void final_k(
    const float* __restrict__ agg2, const float* __restrict__ ep,
    const float* __restrict__ pw1, const float* __restrict__ pw2,
    const float* __restrict__ pb2, const float* __restrict__ bias,
    const float* __restrict__ alpha_p, float* __restrict__ out)
{
    __shared__ float s1w[256], s2w[256], sb[16], sbias[16];
    const int t = threadIdx.x;
    s1w[t] = pw1[t];
    s2w[t] = pw2[t];
    if (t < 16) { sb[t] = pb2[t]; sbias[t] = bias[t]; }
    __syncthreads();
    const int v = blockIdx.x * 256 + t;
    if (v >= N_NODES) return;
    float alpha = *alpha_p;
    float e_[16];
    #pragma unroll
    for (int j4 = 0; j4 < 16; j4 += 4) {
        float4 vv = *(const float4*)(ep + (size_t)v * 16 + j4);
        e_[j4] = vv.x; e_[j4 + 1] = vv.y; e_[j4 + 2] = vv.z; e_[j4 + 3] = vv.w;
    }
    float t2[16];
    #pragma unroll
    for (int c = 0; c < 16; ++c) {
        float s = 0.f;
        #pragma unroll
        for (int j = 0; j < 16; ++j) s = fmaf(e_[j], s1w[j * 16 + c], s);
        t2[c] = s > 0.f ? s : 0.2f * s;
    }
    float o[16];
    #pragma unroll
    for (int c4 = 0; c4 < 16; c4 += 4) {
        float4 ag = *(const float4*)(agg2 + (size_t)v * 16 + c4);
        float agv[4] = {ag.x, ag.y, ag.z, ag.w};
        #pragma unroll
        for (int q = 0; q < 4; ++q) {
            int c = c4 + q;
            float p = sb[c];
            #pragma unroll
            for (int j = 0; j < 16; ++j) p = fmaf(t2[j], s2w[j * 16 + c], p);
            p = p > 0.f ? p : 0.01f * p;
            o[c] = agv[q] + sbias[c] + alpha * p;
        }
    }
    float mx = o[0];
    #pragma unroll
    for (int c = 1; c < 16; ++c) mx = fmaxf(mx, o[c]);
    float se = 0.f;
    #pragma unroll
    for (int c = 0; c < 16; ++c) se += expf(o[c] - mx);
    float lse = mx + logf(se);
    #pragma unroll
    for (int c4 = 0; c4 < 16; c4 += 4)
        *(float4*)(out + (size_t)v * 16 + c4) =
            make_float4(o[c4] - lse, o[c4 + 1] - lse, o[c4 + 2] - lse, o[c4 + 3] - lse);
}

extern "C" void kernel_launch(void* const* d_in, const int* in_sizes, int n_in,
                              void* d_out, int out_size, void* d_ws, size_t ws_size,
                              hipStream_t stream) {
    const float* x    = (const float*)d_in[0];
    const int*   ei   = (const int*)d_in[1];
    const float* alpha= (const float*)d_in[2];
    const float* kr   = (const float*)d_in[3];
    const float* ep   = (const float*)d_in[4];
    const float* W1   = (const float*)d_in[5];
    const float* h1w1 = (const float*)d_in[6];
    const float* h1w2 = (const float*)d_in[7];
    const float* h1b2 = (const float*)d_in[8];
    const float* p1w1 = (const float*)d_in[9];
    const float* p1w2 = (const float*)d_in[10];
    const float* p1b2 = (const float*)d_in[11];
    const float* b1   = (const float*)d_in[12];
    const float* W2   = (const float*)d_in[13];
    const float* h2w1 = (const float*)d_in[14];
    const float* h2w2 = (const float*)d_in[15];
    const float* h2b2 = (const float*)d_in[16];
    const float* p2w1 = (const float*)d_in[17];
    const float* p2w2 = (const float*)d_in[18];
    const float* p2b2 = (const float*)d_in[19];
    const float* b2   = (const float*)d_in[20];
    float* out = (float*)d_out;

    // ---- workspace bump allocator (~242 MB) ----
    char* p = (char*)d_ws;
    auto alloc = [&](size_t bytes) { char* r = p; p += (bytes + 255) & ~(size_t)255; return r; };

    char* r0    = alloc((size_t)64 * M_PAD * 16);          // 51.25 MB: xq (fp8 512B rows), then t1p
    u8*   xq    = (u8*)r0;
    u16*  t1p   = (u16*)r0;
    u16*  aggb  = (u16*)alloc((size_t)N_NODES * H1 * 2);   // 51.2 MB bf16
    char* ebr   = alloc((size_t)E_TOT * HID * 2);          // 83.2 MB: ebd (slot-ordered)
    u16*  ebd   = (u16*)ebr;
    u16*  ebd2  = (u16*)alloc((size_t)E_TOT * NCLS * 2);   // 20.8 MB
    char* xpr   = alloc((size_t)16 * M_PAD * 16);          // 12.81 MB: xp (frag-major x), then xh2p[4][M_PAD][16]
    u16*  xp    = (u16*)xpr;
    float* xh2p = (float*)xpr;
    float* sinv1= (float*)alloc((size_t)N_NODES * 64 * 4); // 12.8 MB layer-1 inv denominators
    u16*  W1p   = (u16*)alloc((size_t)16 * H1 * 16);       // 128 KB
    u16*  p1w2p = (u16*)alloc((size_t)64 * H1 * 16);       // 512 KB
    u16*  w1f   = (u16*)alloc(2048 * 2);                   // mlp1 w1 frags
    u16*  w2f   = (u16*)alloc(4096 * 2);                   // mlp1 w2 frags
    u16*  w3f   = (u16*)alloc(512 * 2);                    // mlp2 w1 frags
    u16*  w4f   = (u16*)alloc(512 * 2);                    // mlp2 w2 frags
    u16*  w2hf  = (u16*)alloc(8192 * 2);                   // W2 hi frags (16 ks x 64 lanes x 8)
    u16*  w2lf  = (u16*)alloc(8192 * 2);                   // W2 lo (residual) frags
    int* src_cnt  = (int*)alloc(N_NODES * 4);
    int* dst_cnt  = (int*)alloc(N_NODES * 4);
    int* src_cur  = (int*)alloc(N_NODES * 4);
    int* dst_cur  = (int*)alloc(N_NODES * 4);
    int* partials = (int*)alloc(2 * NBLK * 4);
    int* src_off  = (int*)alloc((N_NODES + 1) * 4);
    int* dst_off  = (int*)alloc((N_NODES + 1) * 4);
    int* src_list = (int*)alloc((size_t)E_TOT * 4);        // dst-slot ids grouped by src
    int* deid     = (int*)alloc((size_t)E_TOT * 4);        // dst slot -> edge id
    int* dsrc     = (int*)alloc((size_t)E_TOT * 4);        // dst slot -> src node
    float* z2   = (float*)alloc((size_t)N_NODES * NCLS * 4);   // inv2*xh2 fused table
    float* agg2 = (float*)alloc((size_t)N_NODES * NCLS * 4);
    float* inv2 = (float*)alloc((size_t)N_NODES * NCLS * 4);

    const dim3 blk(256);
    const int EB = (E_TOT + 255) / 256;
    const int WB = (N_NODES * 64 + 255) / 256;
    const int GB16 = (N_NODES + 15) / 16;
    const dim3 gmm(512 / 128, M_PAD / 128);                 // (4, 391)
    const int MLPB = (E_TOT / 16 + 3) / 4;

    // ---- CSR build + weight/layout conversion ----
    hipMemsetAsync(src_cnt, 0, (char*)partials - (char*)src_cnt, stream);
    count_k<<<EB, blk, 0, stream>>>(ei, src_cnt, dst_cnt);
    scanA_k<<<2 * NBLK, blk, 0, stream>>>(src_cnt, dst_cnt, partials);
    scanB_k<<<1, 512, 0, stream>>>(partials);
    scanC_k<<<2 * NBLK, blk, 0, stream>>>(src_cnt, dst_cnt, partials, src_off, dst_off);
    fillD_k<<<8 * FBPR, blk, 0, stream>>>(ei, dst_off, dst_cur, deid, dsrc);
    fillS_k<<<8 * FBPR, blk, 0, stream>>>(dsrc, src_off, src_cur, src_list);
    conv_a_k<<<(16 * M_PAD + 255) / 256, blk, 0, stream>>>(x, xp, N_NODES, M_PAD, F_IN);
    conv_b_k<<<(16 * H1 + 255) / 256, blk, 0, stream>>>(W1, W1p, F_IN, H1);
    conv_b_k<<<(64 * H1 + 255) / 256, blk, 0, stream>>>(p1w2, p1w2p, H1, H1);
    wfrag_all_k<<<92, blk, 0, stream>>>(h1w1, h1w2, h2w1, h2w2, W2,
                                        w1f, w2f, w3f, w4f, w2hf, w2lf);

    // ---- layer 1 (edge MLPs + BOTH denominator tables in ONE src_list pass, then the
    //      x@W1 GEMM with fused softmax-scale + fp8 epilogue) ----
    edge_mlps_k<<<MLPB, blk, 0, stream>>>(kr, deid, w1f, w2f, h1b2, w3f, w4f, h2b2, ebd, ebd2);
    ssum_k<<<WB, blk, 0, stream>>>(ebd, ebd2, src_off, src_list, sinv1, inv2);
    mfma_gemm_k<1><<<gmm, blk, 0, stream>>>(xp, W1p, (u16*)xq, N_NODES, M_PAD, H1, F_IN,
                                            nullptr, nullptr, nullptr, nullptr,
                                            nullptr, nullptr, nullptr, sinv1);
    msg1_k<<<WB, blk, 0, stream>>>(ebd, xq, dsrc, dst_off, aggb);
    gemm_t1_k<<<dim3(8, (N_NODES + 63) / 64), blk, 0, stream>>>(ep, p1w1, t1p);   // overwrites xq region
    // fused: h = relu(aggb + b1 + alpha*leaky(t1@p1w2 + p1b2)); xh2 partials = h @ W2 (MFMA)
    mfma_gemm_k<3><<<gmm, blk, 0, stream>>>(t1p, p1w2p, nullptr, N_NODES, M_PAD, H1, H1,
                                            p1b2, aggb, b1, alpha, w2hf, w2lf, xh2p, nullptr);

    // ---- layer 2: z2 = (sum partials)*inv2 -> single L2-resident gather table ----
    red4z_k<<<(N_NODES * 4 + 255) / 256, blk, 0, stream>>>(xh2p, inv2, z2);
    msg2_k<<<GB16, blk, 0, stream>>>(ebd2, z2, dsrc, dst_off, agg2);
    final_k<<<(N_NODES + 255) / 256, blk, 0, stream>>>(agg2, ep, p2w1, p2w2, p2b2, b2, alpha, out);
}